// Round 5
// baseline (1559.628 us; speedup 1.0000x reference)
//
#include <hip/hip_runtime.h>
#include <cstdint>

// Block_32401233281211: SAM-style windowed-attention transformer block.
// I/O dtype: FLOAT32. Internal GEMMs + attention: bf16 MFMA.
// B=8, H=W=64, C=768, heads=12, hd=64, FF=3072, WS=14 -> pad to 70x70,
// 200 windows x 196 tokens = 39200 window-token rows.
// R8: attention half-blocks (~200us, kept).
// R9/R10 lesson: 128^2 tile is LDS-BW-bound at peak (reads 128KB + writes
//   64KB per CU per K-tile > MFMA 1242cyc) -> MfmaUtil pinned ~18% regardless
//   of pipelining. Tile size sets the MFMA:LDS ratio (regime-gate).
// R11 (this round): gemm256 = R10's verified skeleton scaled to 256x256:
//   - BK=64, 512 thr, 8 waves (2Mx4N), acc[8][4]; 64 MFMA per barrier-pair
//   - MFMA 2480cyc vs LDS 2260cyc per K-tile per CU -> compute-bound
//   - prefetch distance = full K-tile compute (~2500cyc) -> vmcnt(8) covered
//   - 4 static LDS arrays (128KB), even/odd unrolled; swizzle unchanged
//     (verified 0 bank conflicts in R9/R10)

typedef unsigned short u16;
typedef __attribute__((ext_vector_type(8))) short short8;   // 8 x bf16
typedef __attribute__((ext_vector_type(4))) float f32x4;

__device__ __forceinline__ u16 f2b(float f) {
    union { float f; unsigned int i; } x; x.f = f;
    unsigned int u = x.i;
    return (u16)((u + 0x7fffu + ((u >> 16) & 1u)) >> 16);   // RNE
}
__device__ __forceinline__ float b2f(u16 u) {
    union { unsigned int i; float f; } x; x.i = ((unsigned int)u) << 16; return x.f;
}

// async global->LDS, 16 B per lane. LDS dest = wave-uniform base + lane*16.
__device__ __forceinline__ void gload16(const u16* g, u16* l) {
    __builtin_amdgcn_global_load_lds(
        (const __attribute__((address_space(1))) unsigned int*)g,
        (__attribute__((address_space(3))) unsigned int*)l, 16, 0, 0);
}

// bijective XCD swizzle (m204)
__device__ __forceinline__ int xcd_swz(int bid, int nwg) {
    int q = nwg >> 3, r = nwg & 7;
    int x = bid & 7, lo = bid >> 3;
    return (x < r ? x * (q + 1) : r * (q + 1) + (x - r) * q) + lo;
}

// ---------------------------------------------------------------- transpose
__global__ __launch_bounds__(256) void transpose_k(
    const float* __restrict__ in, u16* __restrict__ out, int R, int C)
{
    __shared__ float tile[32][33];
    int bpc = C >> 5;
    int r0 = (blockIdx.x / bpc) << 5;
    int c0 = (blockIdx.x % bpc) << 5;
    int lx = threadIdx.x & 31, ly = threadIdx.x >> 5;
#pragma unroll
    for (int s = 0; s < 32; s += 8)
        tile[ly + s][lx] = in[(size_t)(r0 + ly + s) * C + c0 + lx];
    __syncthreads();
#pragma unroll
    for (int s = 0; s < 32; s += 8)
        out[(size_t)(c0 + ly + s) * R + r0 + lx] = f2b(tile[lx][ly + s]);
}

// ---------------------------------------------------------------- layernorm
__global__ __launch_bounds__(256) void ln_kernel(
    const float* __restrict__ in, const float* __restrict__ g,
    const float* __restrict__ beta, u16* __restrict__ out, int windowed,
    int row_base)
{
    __shared__ float sbuf[4];
    int tid = threadIdx.x;
    size_t orow = (size_t)blockIdx.x * 768;
    size_t irow;
    if (windowed) {
        int r = row_base + blockIdx.x;
        int win = r / 196, t = r % 196;
        int p = t / 14, q = t % 14;
        int b = win / 25, wt = win % 25;
        int i = (wt / 5) * 14 + p, j = (wt % 5) * 14 + q;
        if (i >= 64 || j >= 64) {
            out[orow + tid] = 0; out[orow + tid + 256] = 0; out[orow + tid + 512] = 0;
            return;
        }
        irow = (((size_t)b * 64 + i) * 64 + j) * 768;
    } else {
        irow = (size_t)blockIdx.x * 768;
    }
    float v0 = in[irow + tid];
    float v1 = in[irow + tid + 256];
    float v2 = in[irow + tid + 512];
    float s = v0 + v1 + v2;
#pragma unroll
    for (int off = 32; off; off >>= 1) s += __shfl_xor(s, off, 64);
    if ((tid & 63) == 0) sbuf[tid >> 6] = s;
    __syncthreads();
    float mean = (sbuf[0] + sbuf[1] + sbuf[2] + sbuf[3]) * (1.f / 768.f);
    __syncthreads();
    float d0 = v0 - mean, d1 = v1 - mean, d2 = v2 - mean;
    float sq = d0 * d0 + d1 * d1 + d2 * d2;
#pragma unroll
    for (int off = 32; off; off >>= 1) sq += __shfl_xor(sq, off, 64);
    if ((tid & 63) == 0) sbuf[tid >> 6] = sq;
    __syncthreads();
    float var = (sbuf[0] + sbuf[1] + sbuf[2] + sbuf[3]) * (1.f / 768.f);
    float rs = rsqrtf(var + 1e-6f);
    out[orow + tid]       = f2b(d0 * rs * g[tid]       + beta[tid]);
    out[orow + tid + 256] = f2b(d1 * rs * g[tid + 256] + beta[tid + 256]);
    out[orow + tid + 512] = f2b(d2 * rs * g[tid + 512] + beta[tid + 512]);
}

// ---------------------------------------------------------------- GEMM 256x256
// C(MxN) = A(MxK) @ Bt(NxK)^T + bias, bf16 in / f32 acc, MFMA 16x16x32.
// 512 threads = 8 waves (2M x 4N); wave tile 128x64 = acc[8][4].
// LDS: 4 distinct static arrays (As0/As1/Bs0/Bs1, 32 KB each = 128 KB).
// Staging: per wave 4 A + 4 B gload16; slice = 8 rows x 128 B; lane i ->
// row (i>>3), src k-chunk (i&7)^(i>>3) (inverse swizzle), LDS linear.
// Read: frag(row,ks) at row*64 + (((ks*4+quad)^(row&7))*8  (0 conflicts).
// Pipeline per iteration (2 K-tiles, nth = K/128, K%128==0):
//   B | stage(2it+1 -> S1) | vmcnt(8) | B | compute S0   (64 MFMA/wave)
//   B | stage(2it+2 -> S0)?| vmcnt(8/0) | B | compute S1
// Tail M-rows stage garbage (land in adjacent workspace); epilogue skips.

__device__ __forceinline__ short8 lds_frag256(const u16* base, int row, int ks,
                                              int quad) {
    return *(const short8*)(base + row * 64 + ((((ks << 2) + quad) ^ (row & 7)) << 3));
}

__device__ __forceinline__ void compute_tile256(
    const u16* Ab, const u16* Bb, f32x4 (&acc)[8][4],
    int wr, int wc, int quad, int l16)
{
    short8 b_[4][2];
#pragma unroll
    for (int n = 0; n < 4; n++)
#pragma unroll
        for (int ks = 0; ks < 2; ks++)
            b_[n][ks] = lds_frag256(Bb, wc * 64 + n * 16 + l16, ks, quad);
#pragma unroll
    for (int mq = 0; mq < 2; mq++) {
        short8 a_[4][2];
#pragma unroll
        for (int m = 0; m < 4; m++)
#pragma unroll
            for (int ks = 0; ks < 2; ks++)
                a_[m][ks] = lds_frag256(Ab, wr * 128 + mq * 64 + m * 16 + l16, ks, quad);
        __builtin_amdgcn_s_setprio(1);
#pragma unroll
        for (int m = 0; m < 4; m++)
#pragma unroll
            for (int n = 0; n < 4; n++)
#pragma unroll
                for (int ks = 0; ks < 2; ks++)
                    acc[mq * 4 + m][n] = __builtin_amdgcn_mfma_f32_16x16x32_bf16(
                        a_[m][ks], b_[n][ks], acc[mq * 4 + m][n], 0, 0, 0);
        __builtin_amdgcn_s_setprio(0);
    }
}

template <int EPI>
__global__ __launch_bounds__(512) void gemm256(
    const u16* __restrict__ A, const u16* __restrict__ Bt,
    const float* __restrict__ bias, void* __restrict__ CoutV,
    const float* __restrict__ resid, int M, int N, int K, int row_base)
{
    __shared__ __align__(16) u16 As0[256 * 64];
    __shared__ __align__(16) u16 As1[256 * 64];
    __shared__ __align__(16) u16 Bs0[256 * 64];
    __shared__ __align__(16) u16 Bs1[256 * 64];

    const int tid = threadIdx.x;
    const int lane = tid & 63, wave = tid >> 6;        // 8 waves
    const int wr = wave >> 2, wc = wave & 3;           // 2 x 4
    const int quad = lane >> 4, l16 = lane & 15;
    const int ntile = N / 256;
    const int swz = xcd_swz(blockIdx.x, gridDim.x);
    const int m0 = (swz / ntile) * 256;
    const int n0 = (swz % ntile) * 256;

    // staging lane constants (verified swizzle, 0 bank conflicts)
    const int rl = lane >> 3;
    const int cl = ((lane & 7) ^ rl) << 3;
    int aoff[4], boff[4];
#pragma unroll
    for (int q = 0; q < 4; q++) {
        aoff[q] = (m0 + wave * 32 + q * 8 + rl) * K + cl;
        boff[q] = (n0 + wave * 32 + q * 8 + rl) * K + cl;
    }
    const int lws = wave * 2048;      // wave's staging base (elems)

    f32x4 acc[8][4] = {};
    const int nth = K >> 7;           // K/128, 2 K-tiles per iteration

    // prologue: tile 0 -> S0
#pragma unroll
    for (int q = 0; q < 4; q++) {
        gload16(A  + aoff[q], As0 + lws + q * 512);
        gload16(Bt + boff[q], Bs0 + lws + q * 512);
    }

#pragma unroll 1
    for (int it = 0; it < nth; ++it) {
        // ---- phase A: stage tile 2it+1 -> S1, compute tile 2it from S0
        __builtin_amdgcn_sched_barrier(0);
        __builtin_amdgcn_s_barrier();            // S1 reads (prev iter) done
        __builtin_amdgcn_sched_barrier(0);
        {
            const int k1 = (2 * it + 1) << 6;
#pragma unroll
            for (int q = 0; q < 4; q++) {
                gload16(A  + aoff[q] + k1, As1 + lws + q * 512);
                gload16(Bt + boff[q] + k1, Bs1 + lws + q * 512);
            }
        }
        __builtin_amdgcn_sched_barrier(0);
        asm volatile("s_waitcnt vmcnt(8)" ::: "memory");   // tile 2it resident
        __builtin_amdgcn_sched_barrier(0);
        __builtin_amdgcn_s_barrier();            // ... for all waves
        __builtin_amdgcn_sched_barrier(0);
        compute_tile256(As0, Bs0, acc, wr, wc, quad, l16);

        // ---- phase B: stage tile 2it+2 -> S0 (if any), compute tile 2it+1
        __builtin_amdgcn_sched_barrier(0);
        __builtin_amdgcn_s_barrier();            // S0 reads done
        __builtin_amdgcn_sched_barrier(0);
        if (it + 1 < nth) {
            const int k2 = (2 * it + 2) << 6;
#pragma unroll
            for (int q = 0; q < 4; q++) {
                gload16(A  + aoff[q] + k2, As0 + lws + q * 512);
                gload16(Bt + boff[q] + k2, Bs0 + lws + q * 512);
            }
            __builtin_amdgcn_sched_barrier(0);
            asm volatile("s_waitcnt vmcnt(8)" ::: "memory");
        } else {
            __builtin_amdgcn_sched_barrier(0);
            asm volatile("s_waitcnt vmcnt(0)" ::: "memory");
        }
        __builtin_amdgcn_sched_barrier(0);
        __builtin_amdgcn_s_barrier();
        __builtin_amdgcn_sched_barrier(0);
        compute_tile256(As1, Bs1, acc, wr, wc, quad, l16);
    }

    // ---- epilogue
#pragma unroll
    for (int mi = 0; mi < 8; mi++) {
#pragma unroll
        for (int ni = 0; ni < 4; ni++) {
            const int gn = n0 + wc * 64 + ni * 16 + l16;
            const float bv = bias[gn];
#pragma unroll
            for (int r = 0; r < 4; r++) {
                const int row = m0 + wr * 128 + mi * 16 + quad * 4 + r;
                if (row >= M) continue;
                float v = acc[mi][ni][r] + bv;
                if (EPI == 0) {
                    ((u16*)CoutV)[(size_t)row * N + gn] = f2b(v);
                } else if (EPI == 1) {
                    int grow = row_base + row;
                    int win = grow / 196, t = grow % 196;
                    int p = t / 14, q = t % 14;
                    int b_ = win / 25, wt = win % 25;
                    int i = (wt / 5) * 14 + p, j = (wt % 5) * 14 + q;
                    if (i < 64 && j < 64) {
                        size_t idx = (((size_t)b_ * 64 + i) * 64 + j) * 768 + gn;
                        ((float*)CoutV)[idx] = resid[idx] + v;
                    }
                } else if (EPI == 2) {
                    float gl = 0.5f * v * (1.0f + erff(v * 0.70710678118654752f));
                    ((u16*)CoutV)[(size_t)row * N + gn] = f2b(gl);
                } else {
                    size_t idx = (size_t)(row_base + row) * 768 + gn;
                    ((float*)CoutV)[idx] = resid[idx] + v;
                }
            }
        }
    }
}

// ---------------------------------------------------------------- attention v5
// (unchanged from R8 — verified passing)
#define AT_W 72
#define PB_W 40

__global__ __launch_bounds__(256) void attn_mfma(
    const u16* __restrict__ qkv,          // [nw*196][2304] = [..][3][12][64]
    const float* __restrict__ relh, const float* __restrict__ relw, // [27][64]
    u16* __restrict__ out)                // [nw*196][768]
{
    __shared__ __align__(16) u16 pbuf[4][32 * PB_W];     // 10240 B (rel_ext alias)
    __shared__ __align__(16) u16 Kc[64 * AT_W];          //  9216 B
    __shared__ __align__(16) u16 Vt[64 * AT_W];          //  9216 B
    u16* rel_ext = &pbuf[0][0];                          // 128*32*2 = 8192 B

    const int nwg = gridDim.x;
    const int swzb = xcd_swz(blockIdx.x, nwg);
    const int win = swzb / 24, rem = swzb % 24;
    const int head = rem >> 1, half = rem & 1;
    const int row0 = half * 128;
    const int tid = threadIdx.x, lane = tid & 63, wave = tid >> 6;
    const int quad = lane >> 4, l16 = lane & 15;
    const size_t base = (size_t)win * 196 * 2304 + (size_t)head * 64;

    short8 qf[2][2];
#pragma unroll
    for (int mi = 0; mi < 2; mi++) {
        int tok = row0 + wave * 32 + mi * 16 + l16;
        int rt = tok < 196 ? tok : 195;
        const u16* qp = qkv + base + (size_t)rt * 2304 + quad * 8;
        qf[mi][0] = *(const short8*)(qp);
        qf[mi][1] = *(const short8*)(qp + 32);
    }

    for (int e = tid; e < 64 * 64; e += 256) {
        int rr = e >> 6, cc = e & 63;
        float v = 0.f;
        if (rr < 27)      v = 8.f * relh[rr * 64 + cc];
        else if (rr < 54) v = 8.f * relw[(rr - 27) * 64 + cc];
        Kc[rr * AT_W + cc] = f2b(v);
    }
    if (tid < 128) {
        u16* rp = rel_ext + tid * 32;
        uint4 z = make_uint4(0u, 0u, 0u, 0u);
        *(uint4*)(rp) = z; *(uint4*)(rp + 8) = z;
        *(uint4*)(rp + 16) = z; *(uint4*)(rp + 24) = z;
        rp[31] = f2b(-1e30f);
    }
    __syncthreads();

#pragma unroll
    for (int cb = 0; cb < 2; cb++) {
#pragma unroll
        for (int nt = 0; nt < 2; nt++) {
            const u16* kp_ = Kc + (cb * 32 + nt * 16 + l16) * AT_W + quad * 8;
            short8 b0 = *(const short8*)(kp_);
            short8 b1 = *(const short8*)(kp_ + 32);
            int i = cb * 32 + nt * 16 + l16;
#pragma unroll
            for (int mi = 0; mi < 2; mi++) {
                f32x4 c = {};
                c = __builtin_amdgcn_mfma_f32_16x16x32_bf16(qf[mi][0], b0, c, 0, 0, 0);
                c = __builtin_amdgcn_mfma_f32_16x16x32_bf16(qf[mi][1], b1, c, 0, 0, 0);
#pragma unroll
                for (int r = 0; r < 4; r++) {
                    int row = wave * 32 + mi * 16 + quad * 4 + r;
                    int grow = row0 + row;
                    int rowB = grow < 196 ? grow : 195;
                    int p = rowB / 14, qq = rowB % 14;
                    if (i < 27) {
                        int t = p + 13 - i;
                        if (t >= 0 && t < 14) rel_ext[row * 32 + t] = f2b(c[r]);
                    } else if (i < 54) {
                        int t = qq + 13 - (i - 27);
                        if (t >= 0 && t < 14) rel_ext[row * 32 + 14 + t] = f2b(c[r]);
                    }
                }
            }
        }
    }
    short8 qe[2];
#pragma unroll
    for (int mi = 0; mi < 2; mi++)
        qe[mi] = *(const short8*)(rel_ext + (wave * 32 + mi * 16 + l16) * 32 + quad * 8);

    f32x4 acc[2][4] = {};
    float ml_[2][4], ll_[2][4];
#pragma unroll
    for (int mi = 0; mi < 2; mi++)
#pragma unroll
        for (int r = 0; r < 4; r++) { ml_[mi][r] = -1e30f; ll_[mi][r] = 0.f; }

#pragma unroll 1
    for (int c = 0; c < 4; c++) {
        const int kbase = c * 64;
        __syncthreads();
        {
            int key = tid >> 2;
            int cg  = (tid & 3) << 4;
            int gk = kbase + key;
            uint4 k0 = make_uint4(0u,0u,0u,0u), k1 = k0, v0 = k0, v1 = k0;
            if (gk < 196) {
                const u16* kp_ = qkv + base + 768  + (size_t)gk * 2304 + cg;
                const u16* vp_ = qkv + base + 1536 + (size_t)gk * 2304 + cg;
                k0 = *(const uint4*)(kp_); k1 = *(const uint4*)(kp_ + 8);
                v0 = *(const uint4*)(vp_); v1 = *(const uint4*)(vp_ + 8);
            }
            *(uint4*)(Kc + key * AT_W + cg)     = k0;
            *(uint4*)(Kc + key * AT_W + cg + 8) = k1;
            union { uint4 u; u16 h[8]; } a, b; a.u = v0; b.u = v1;
#pragma unroll
            for (int i = 0; i < 8; i++) Vt[(cg + i) * AT_W + key] = a.h[i];
#pragma unroll
            for (int i = 0; i < 8; i++) Vt[(cg + 8 + i) * AT_W + key] = b.h[i];
        }
        __syncthreads();

        short8 bo[4];
        {
            const u16 one = 0x3F80;
#pragma unroll
            for (int nt = 0; nt < 4; nt++) {
                int key = kbase + nt * 16 + l16;
                int inval = key >= 196;
                int kp = key / 14, kq = key - kp * 14;
                union { short8 s; u16 h[8]; } u;
#pragma unroll
                for (int j = 0; j < 8; j++) {
                    int t = quad * 8 + j;
                    u16 v = 0;
                    if (!inval && t == kp) v = one;
                    if (!inval && t >= 14 && (t - 14) == kq) v = one;
                    if (inval && t == 31) v = one;
                    u.h[j] = v;
                }
                bo[nt] = u.s;
            }
        }

        f32x4 s23[2][2];
#pragma unroll
        for (int mi = 0; mi < 2; mi++) {
            f32x4 s[4];
            __builtin_amdgcn_s_setprio(1);
#pragma unroll
            for (int nt = 0; nt < 4; nt++) {
                const u16* kp_ = Kc + (nt * 16 + l16) * AT_W + quad * 8;
                short8 kf0 = *(const short8*)(kp_);
                short8 kf1 = *(const short8*)(kp_ + 32);
                f32x4 t = {};
                t = __builtin_amdgcn_mfma_f32_16x16x32_bf16(qf[mi][0], kf0, t, 0, 0, 0);
                t = __builtin_amdgcn_mfma_f32_16x16x32_bf16(qf[mi][1], kf1, t, 0, 0, 0);
                t = __builtin_amdgcn_mfma_f32_16x16x32_bf16(qe[mi],    bo[nt], t, 0, 0, 0);
                s[nt] = t * 0.125f;
            }
            __builtin_amdgcn_s_setprio(0);
#pragma unroll
            for (int r = 0; r < 4; r++) {
                float mx = fmaxf(fmaxf(s[0][r], s[1][r]), fmaxf(s[2][r], s[3][r]));
#pragma unroll
                for (int off = 8; off; off >>= 1) mx = fmaxf(mx, __shfl_xor(mx, off, 16));
                float mo = ml_[mi][r];
                float mn = fmaxf(mo, mx);
                float alpha = __expf(mo - mn);
                ml_[mi][r] = mn;
                float p0 = __expf(s[0][r] - mn), p1 = __expf(s[1][r] - mn);
                float p2 = __expf(s[2][r] - mn), p3 = __expf(s[3][r] - mn);
                float ps = (p0 + p1) + (p2 + p3);
#pragma unroll
                for (int off = 8; off; off >>= 1) ps += __shfl_xor(ps, off, 16);
                ll_[mi][r] = ll_[mi][r] * alpha + ps;
#pragma unroll
                for (int ni = 0; ni < 4; ni++) acc[mi][ni][r] *= alpha;
                s[0][r] = p0; s[1][r] = p1; s[2][r] = p2; s[3][r] = p3;
            }
#pragma unroll
            for (int nt = 0; nt < 2; nt++)
#pragma unroll
                for (int r = 0; r < 4; r++)
                    pbuf[wave][(mi * 16 + quad * 4 + r) * PB_W + nt * 16 + l16] = f2b(s[nt][r]);
            s23[mi][0] = s[2]; s23[mi][1] = s[3];
        }

        __builtin_amdgcn_s_setprio(1);
#pragma unroll
        for (int mi = 0; mi < 2; mi++) {
            short8 pf = *(const short8*)(pbuf[wave] + (mi * 16 + l16) * PB_W + quad * 8);
#pragma unroll
            for (int ni = 0; ni < 4; ni++) {
                short8 vfn = *(const short8*)(Vt + (ni * 16 + l16) * AT_W + quad * 8);
                acc[mi][ni] = __builtin_amdgcn_mfma_f32_16x16x32_bf16(pf, vfn, acc[mi][ni], 0, 0, 0);
            }
        }
        __builtin_amdgcn_s_setprio(0);
#pragma unroll
        for (int mi = 0; mi < 2; mi++)
#pragma unroll
            for (int h = 0; h < 2; h++)
#pragma unroll
                for (int r = 0; r < 4; r++)
                    pbuf[wave][(mi * 16 + quad * 4 + r) * PB_W + h * 16 + l16] = f2b(s23[mi][h][r]);
        __builtin_amdgcn_s_setprio(1);
#pragma unroll
        for (int mi = 0; mi < 2; mi++) {
            short8 pf = *(const short8*)(pbuf[wave] + (mi * 16 + l16) * PB_W + quad * 8);
#pragma unroll
            for (int ni = 0; ni < 4; ni++) {
                short8 vfn = *(const short8*)(Vt + (ni * 16 + l16) * AT_W + 32 + quad * 8);
                acc[mi][ni] = __builtin_amdgcn_mfma_f32_16x16x32_bf16(pf, vfn, acc[mi][ni], 0, 0, 0);
            }
        }
        __builtin_amdgcn_s_setprio(0);
    }

#pragma unroll
    for (int mi = 0; mi < 2; mi++)
#pragma unroll
        for (int r = 0; r < 4; r++) {
            int tok = row0 + wave * 32 + mi * 16 + quad * 4 + r;
            if (tok < 196) {
                float inv = 1.f / ll_[mi][r];
                size_t ob = (size_t)(win * 196 + tok) * 768 + head * 64;
#pragma unroll
                for (int ni = 0; ni < 4; ni++)
                    out[ob + ni * 16 + l16] = f2b(acc[mi][ni][r] * inv);
            }
        }
}

// ---------------------------------------------------------------- launch
extern "C" void kernel_launch(void* const* d_in, const int* in_sizes, int n_in,
                              void* d_out, int out_size, void* d_ws, size_t ws_size,
                              hipStream_t stream)
{
    const float* x      = (const float*)d_in[0];
    const float* g1     = (const float*)d_in[1];
    const float* beta1  = (const float*)d_in[2];
    const float* w_qkv  = (const float*)d_in[3];
    const float* b_qkv  = (const float*)d_in[4];
    const float* w_proj = (const float*)d_in[5];
    const float* b_proj = (const float*)d_in[6];
    const float* rph    = (const float*)d_in[7];
    const float* rpw    = (const float*)d_in[8];
    const float* g2     = (const float*)d_in[9];
    const float* beta2  = (const float*)d_in[10];
    const float* w_fc1  = (const float*)d_in[11];
    const float* b_fc1  = (const float*)d_in[12];
    const float* w_fc2  = (const float*)d_in[13];
    const float* b_fc2  = (const float*)d_in[14];
    float* out = (float*)d_out;

    const size_t WT = 14155776;
    size_t b1 = 0, b2 = 0;
    int nc = 0, mc = 0;
    auto fits = [&](int a, int m) -> bool {
        size_t rows = (size_t)(200 / a) * 196, toks = (size_t)32768 / m;
        size_t bb1 = rows * 768 * 2 >= toks * 768 * 2 ? rows * 768 * 2 : toks * 768 * 2;
        size_t bb2 = rows * 2304 * 2 >= toks * 3072 * 2 ? rows * 2304 * 2 : toks * 3072 * 2;
        if (WT + bb1 + bb2 <= ws_size) { b1 = bb1; b2 = bb2; nc = a; mc = m; return true; }
        return false;
    };
    if (!fits(1, 1) && !fits(1, 2) && !fits(2, 2) && !fits(2, 4) && !fits(4, 4))
        return;   // diagnostic: leaves d_out untouched

    char* ws = (char*)d_ws;
    u16* wt0 = (u16*)ws;                               // qkv^T  2304x768
    u16* wt1 = wt0 + 2304 * 768;                       // proj^T  768x768
    u16* wt2 = wt1 + 768 * 768;                        // fc1^T  3072x768
    u16* wt3 = wt2 + 3072 * 768;                       // fc2^T   768x3072
    u16* buf1 = (u16*)(ws + WT);
    u16* buf2 = (u16*)(ws + WT + b1);

    dim3 blk(256), blk5(512);

    transpose_k<<<(768/32)*(2304/32), blk, 0, stream>>>(w_qkv,  wt0, 768, 2304);
    transpose_k<<<(768/32)*(768/32),  blk, 0, stream>>>(w_proj, wt1, 768, 768);
    transpose_k<<<(768/32)*(3072/32), blk, 0, stream>>>(w_fc1,  wt2, 768, 3072);
    transpose_k<<<(3072/32)*(768/32), blk, 0, stream>>>(w_fc2,  wt3, 3072, 768);

    // ---- attention phase: nc chunks of (200/nc) windows ----
    {
        const int nw = 200 / nc, rows = nw * 196;
        const int mt = (rows + 255) / 256;
        for (int c = 0; c < nc; c++) {
            const int rb = c * rows;
            ln_kernel<<<rows, blk, 0, stream>>>(x, g1, beta1, buf1, 1, rb);
            gemm256<0><<<dim3(mt * (2304/256)), blk5, 0, stream>>>(
                buf1, wt0, b_qkv, buf2, nullptr, rows, 2304, 768, 0);
            attn_mfma<<<nw * 24, blk, 0, stream>>>(buf2, rph, rpw, buf1);
            gemm256<1><<<dim3(mt * (768/256)), blk5, 0, stream>>>(
                buf1, wt1, b_proj, out, x, rows, 768, 768, rb);
        }
    }

    // ---- MLP phase: mc chunks of (32768/mc) tokens ----
    {
        const int tk = 32768 / mc;
        const int mt2 = (tk + 255) / 256;
        for (int c = 0; c < mc; c++) {
            const int rb = c * tk;
            ln_kernel<<<tk, blk, 0, stream>>>(
                out + (size_t)rb * 768, g2, beta2, buf1, 0, 0);
            gemm256<2><<<dim3(mt2 * (3072/256)), blk5, 0, stream>>>(
                buf1, wt2, b_fc1, buf2, nullptr, tk, 3072, 768, 0);
            gemm256<3><<<dim3(mt2 * (768/256)), blk5, 0, stream>>>(
                buf2, wt3, b_fc2, out, out, tk, 768, 3072, rb);
        }
    }
}

// Round 6
// 1548.482 us; speedup vs baseline: 1.0072x; 1.0072x over previous
//
#include <hip/hip_runtime.h>
#include <cstdint>

// Block_32401233281211: SAM-style windowed-attention transformer block.
// I/O dtype: FLOAT32. Internal GEMMs + attention: bf16 MFMA.
// B=8, H=W=64, C=768, heads=12, hd=64, FF=3072, WS=14 -> pad to 70x70,
// 200 windows x 196 tokens = 39200 window-token rows.
// R8: attention half-blocks (~200us, kept).
// R9-R11 lesson: stage-all/wait-all/compute-all (2-phase) caps at ~615 TF
//   per-CU regardless of tile size or LDS aliasing structure (matches m233's
//   measured 2-phase ceiling). The read-burst and MFMA-burst serialize and
//   the 1-phase prefetch lead exposes load latency.
// R12 (this round): 4-slot BK=32 lead-3 pipeline (T3/T4 ledger-verified):
//   - 8 static 16KB LDS arrays (slots 0-3 x A,B); loop unrolled x4 so all
//     LDS indexing is compile-time (no runtime dbuf indexing)
//   - per tile: B1 | stage t+3 | vmcnt(12) | B2 | compute-in-4-quadrants
//     vmcnt(12) keeps tiles t+1..t+3 (12 loads) in flight across barriers;
//     epilogue ramps 12->8->4->0
//   - quadrant sub-phases let ds_reads of q+1 overlap MFMA of q; setprio(T5)
//   - 64B-row swizzle: chunk' = kc ^ ((row>>1)&3), inverse-applied on the
//     global source (involution); read hits each bank exactly 2x (free)

typedef unsigned short u16;
typedef __attribute__((ext_vector_type(8))) short short8;   // 8 x bf16
typedef __attribute__((ext_vector_type(4))) float f32x4;

__device__ __forceinline__ u16 f2b(float f) {
    union { float f; unsigned int i; } x; x.f = f;
    unsigned int u = x.i;
    return (u16)((u + 0x7fffu + ((u >> 16) & 1u)) >> 16);   // RNE
}
__device__ __forceinline__ float b2f(u16 u) {
    union { unsigned int i; float f; } x; x.i = ((unsigned int)u) << 16; return x.f;
}

// async global->LDS, 16 B per lane. LDS dest = wave-uniform base + lane*16.
__device__ __forceinline__ void gload16(const u16* g, u16* l) {
    __builtin_amdgcn_global_load_lds(
        (const __attribute__((address_space(1))) unsigned int*)g,
        (__attribute__((address_space(3))) unsigned int*)l, 16, 0, 0);
}

// bijective XCD swizzle (m204)
__device__ __forceinline__ int xcd_swz(int bid, int nwg) {
    int q = nwg >> 3, r = nwg & 7;
    int x = bid & 7, lo = bid >> 3;
    return (x < r ? x * (q + 1) : r * (q + 1) + (x - r) * q) + lo;
}

// ---------------------------------------------------------------- transpose
__global__ __launch_bounds__(256) void transpose_k(
    const float* __restrict__ in, u16* __restrict__ out, int R, int C)
{
    __shared__ float tile[32][33];
    int bpc = C >> 5;
    int r0 = (blockIdx.x / bpc) << 5;
    int c0 = (blockIdx.x % bpc) << 5;
    int lx = threadIdx.x & 31, ly = threadIdx.x >> 5;
#pragma unroll
    for (int s = 0; s < 32; s += 8)
        tile[ly + s][lx] = in[(size_t)(r0 + ly + s) * C + c0 + lx];
    __syncthreads();
#pragma unroll
    for (int s = 0; s < 32; s += 8)
        out[(size_t)(c0 + ly + s) * R + r0 + lx] = f2b(tile[lx][ly + s]);
}

// ---------------------------------------------------------------- layernorm
__global__ __launch_bounds__(256) void ln_kernel(
    const float* __restrict__ in, const float* __restrict__ g,
    const float* __restrict__ beta, u16* __restrict__ out, int windowed,
    int row_base)
{
    __shared__ float sbuf[4];
    int tid = threadIdx.x;
    size_t orow = (size_t)blockIdx.x * 768;
    size_t irow;
    if (windowed) {
        int r = row_base + blockIdx.x;
        int win = r / 196, t = r % 196;
        int p = t / 14, q = t % 14;
        int b = win / 25, wt = win % 25;
        int i = (wt / 5) * 14 + p, j = (wt % 5) * 14 + q;
        if (i >= 64 || j >= 64) {
            out[orow + tid] = 0; out[orow + tid + 256] = 0; out[orow + tid + 512] = 0;
            return;
        }
        irow = (((size_t)b * 64 + i) * 64 + j) * 768;
    } else {
        irow = (size_t)blockIdx.x * 768;
    }
    float v0 = in[irow + tid];
    float v1 = in[irow + tid + 256];
    float v2 = in[irow + tid + 512];
    float s = v0 + v1 + v2;
#pragma unroll
    for (int off = 32; off; off >>= 1) s += __shfl_xor(s, off, 64);
    if ((tid & 63) == 0) sbuf[tid >> 6] = s;
    __syncthreads();
    float mean = (sbuf[0] + sbuf[1] + sbuf[2] + sbuf[3]) * (1.f / 768.f);
    __syncthreads();
    float d0 = v0 - mean, d1 = v1 - mean, d2 = v2 - mean;
    float sq = d0 * d0 + d1 * d1 + d2 * d2;
#pragma unroll
    for (int off = 32; off; off >>= 1) sq += __shfl_xor(sq, off, 64);
    if ((tid & 63) == 0) sbuf[tid >> 6] = sq;
    __syncthreads();
    float var = (sbuf[0] + sbuf[1] + sbuf[2] + sbuf[3]) * (1.f / 768.f);
    float rs = rsqrtf(var + 1e-6f);
    out[orow + tid]       = f2b(d0 * rs * g[tid]       + beta[tid]);
    out[orow + tid + 256] = f2b(d1 * rs * g[tid + 256] + beta[tid + 256]);
    out[orow + tid + 512] = f2b(d2 * rs * g[tid + 512] + beta[tid + 512]);
}

// ---------------------------------------------------------------- GEMM 256x256
// C(MxN) = A(MxK) @ Bt(NxK)^T + bias, bf16 in / f32 acc, MFMA 16x16x32.
// 512 threads = 8 waves (2M x 4N); wave tile 128x64 = acc[8][4]. BK=32.
// LDS slots: tile t -> slot t&3; panel = 256 rows x 32 elems (64 B rows).
// Swizzle: row r holds k-chunk kc at chunk index kc ^ ((r>>1)&3) (16B chunks).
// Staging: per tile 2 A-units + 2 B-units; unit = 8KB (512thr x 16B); lane l
// of wave w covers row w*16 + (l>>2) (+u*128), chunk l&3 -> global kc =
// (l&3) ^ ((row>>1)&3) (involution). gload LDS base = wave-uniform.
// Pipeline per tile t:  B1 | stage t+3 | vmcnt(12/8/4/0) | B2 | 4 quadrants.
// Requires K % 128 == 0 (nt = K/32 divisible by 4): K = 768, 3072 both OK.
// Tail M-rows stage garbage (land in adjacent workspace); epilogue skips.

__device__ __forceinline__ short8 ldsf(const u16* P, int r, int quad) {
    return *(const short8*)(P + r * 32 + ((quad ^ ((r >> 1) & 3)) << 3));
}

__device__ __forceinline__ void comp32(const u16* __restrict__ Ap,
                                       const u16* __restrict__ Bp,
                                       f32x4 (&acc)[8][4],
                                       int wr, int wc, int quad, int l16)
{
    short8 a[4], b[4];
    // ---- quadrant (0,0): rows 0-63 of wave tile, cols 0-31
#pragma unroll
    for (int n = 0; n < 2; n++) b[n] = ldsf(Bp, wc * 64 + n * 16 + l16, quad);
#pragma unroll
    for (int m = 0; m < 4; m++) a[m] = ldsf(Ap, wr * 128 + m * 16 + l16, quad);
    __builtin_amdgcn_s_setprio(1);
#pragma unroll
    for (int m = 0; m < 4; m++)
#pragma unroll
        for (int n = 0; n < 2; n++)
            acc[m][n] = __builtin_amdgcn_mfma_f32_16x16x32_bf16(
                a[m], b[n], acc[m][n], 0, 0, 0);
    __builtin_amdgcn_s_setprio(0);
    // ---- quadrant (0,1): cols 32-63
#pragma unroll
    for (int n = 0; n < 2; n++) b[2 + n] = ldsf(Bp, wc * 64 + (2 + n) * 16 + l16, quad);
    __builtin_amdgcn_s_setprio(1);
#pragma unroll
    for (int m = 0; m < 4; m++)
#pragma unroll
        for (int n = 0; n < 2; n++)
            acc[m][2 + n] = __builtin_amdgcn_mfma_f32_16x16x32_bf16(
                a[m], b[2 + n], acc[m][2 + n], 0, 0, 0);
    __builtin_amdgcn_s_setprio(0);
    // ---- quadrant (1,1): rows 64-127, cols 32-63 (reload A, reuse b[2..3])
#pragma unroll
    for (int m = 0; m < 4; m++) a[m] = ldsf(Ap, wr * 128 + 64 + m * 16 + l16, quad);
    __builtin_amdgcn_s_setprio(1);
#pragma unroll
    for (int m = 0; m < 4; m++)
#pragma unroll
        for (int n = 0; n < 2; n++)
            acc[4 + m][2 + n] = __builtin_amdgcn_mfma_f32_16x16x32_bf16(
                a[m], b[2 + n], acc[4 + m][2 + n], 0, 0, 0);
    __builtin_amdgcn_s_setprio(0);
    // ---- quadrant (1,0): rows 64-127, cols 0-31 (reuse a, b[0..1])
    __builtin_amdgcn_s_setprio(1);
#pragma unroll
    for (int m = 0; m < 4; m++)
#pragma unroll
        for (int n = 0; n < 2; n++)
            acc[4 + m][n] = __builtin_amdgcn_mfma_f32_16x16x32_bf16(
                a[m], b[n], acc[4 + m][n], 0, 0, 0);
    __builtin_amdgcn_s_setprio(0);
}

#define STAGE4(SA, SB, TT)                                                 \
    if ((TT) < nt) {                                                       \
        const size_t kk = (size_t)((TT) << 5);                             \
        gload16(A  + aoff0 + kk, (SA) + wbase);                            \
        gload16(A  + aoff1 + kk, (SA) + 4096 + wbase);                     \
        gload16(Bt + boff0 + kk, (SB) + wbase);                            \
        gload16(Bt + boff1 + kk, (SB) + 4096 + wbase);                     \
    }

#define GSTEP(CA, CB, SA, SB, TT)                                          \
    {                                                                      \
        __builtin_amdgcn_sched_barrier(0);                                 \
        __builtin_amdgcn_s_barrier();   /* old readers of stage slot done */ \
        __builtin_amdgcn_sched_barrier(0);                                 \
        STAGE4(SA, SB, (TT) + 3);                                          \
        __builtin_amdgcn_sched_barrier(0);                                 \
        {                                                                  \
            const int d = nt - 1 - (TT);                                   \
            if (d >= 3)      asm volatile("s_waitcnt vmcnt(12)" ::: "memory"); \
            else if (d == 2) asm volatile("s_waitcnt vmcnt(8)"  ::: "memory"); \
            else if (d == 1) asm volatile("s_waitcnt vmcnt(4)"  ::: "memory"); \
            else             asm volatile("s_waitcnt vmcnt(0)"  ::: "memory"); \
        }                                                                  \
        __builtin_amdgcn_sched_barrier(0);                                 \
        __builtin_amdgcn_s_barrier();   /* tile TT resident for all waves */ \
        __builtin_amdgcn_sched_barrier(0);                                 \
        comp32(CA, CB, acc, wr, wc, quad, l16);                            \
    }

template <int EPI>
__global__ __launch_bounds__(512) void gemm256(
    const u16* __restrict__ A, const u16* __restrict__ Bt,
    const float* __restrict__ bias, void* __restrict__ CoutV,
    const float* __restrict__ resid, int M, int N, int K, int row_base)
{
    __shared__ __align__(16) u16 As0[256 * 32];
    __shared__ __align__(16) u16 As1[256 * 32];
    __shared__ __align__(16) u16 As2[256 * 32];
    __shared__ __align__(16) u16 As3[256 * 32];
    __shared__ __align__(16) u16 Bs0[256 * 32];
    __shared__ __align__(16) u16 Bs1[256 * 32];
    __shared__ __align__(16) u16 Bs2[256 * 32];
    __shared__ __align__(16) u16 Bs3[256 * 32];

    const int tid = threadIdx.x;
    const int lane = tid & 63, wave = tid >> 6;        // 8 waves
    const int wr = wave >> 2, wc = wave & 3;           // 2 x 4
    const int quad = lane >> 4, l16 = lane & 15;
    const int ntile = N / 256;
    const int swz = xcd_swz(blockIdx.x, gridDim.x);
    const int m0 = (swz / ntile) * 256;
    const int n0 = (swz % ntile) * 256;

    // staging lane constants (swizzle involution; see header comment)
    const int rA   = (wave << 4) + (lane >> 2);        // panel row 0..127
    const int kcol = (((lane & 3) ^ ((rA >> 1) & 3)) << 3);
    const size_t aoff0 = (size_t)(m0 + rA) * K + kcol;
    const size_t aoff1 = aoff0 + (size_t)128 * K;
    const size_t boff0 = (size_t)(n0 + rA) * K + kcol;
    const size_t boff1 = boff0 + (size_t)128 * K;
    const int wbase = wave * 512;                      // wave-uniform LDS base

    f32x4 acc[8][4] = {};
    const int nt = K >> 5;                             // K/32, divisible by 4

    // prologue: stage tiles 0,1,2 into slots 0,1,2
    STAGE4(As0, Bs0, 0);
    STAGE4(As1, Bs1, 1);
    STAGE4(As2, Bs2, 2);

#pragma unroll 1
    for (int t = 0; t < nt; t += 4) {
        GSTEP(As0, Bs0, As3, Bs3, t);       // compute slot0, stage t+3 -> slot3
        GSTEP(As1, Bs1, As0, Bs0, t + 1);   // stage t+4 -> slot0
        GSTEP(As2, Bs2, As1, Bs1, t + 2);
        GSTEP(As3, Bs3, As2, Bs2, t + 3);
    }

    // ---- epilogue
#pragma unroll
    for (int mi = 0; mi < 8; mi++) {
#pragma unroll
        for (int ni = 0; ni < 4; ni++) {
            const int gn = n0 + wc * 64 + ni * 16 + l16;
            const float bv = bias[gn];
#pragma unroll
            for (int r = 0; r < 4; r++) {
                const int row = m0 + wr * 128 + mi * 16 + quad * 4 + r;
                if (row >= M) continue;
                float v = acc[mi][ni][r] + bv;
                if (EPI == 0) {
                    ((u16*)CoutV)[(size_t)row * N + gn] = f2b(v);
                } else if (EPI == 1) {
                    int grow = row_base + row;
                    int win = grow / 196, t = grow % 196;
                    int p = t / 14, q = t % 14;
                    int b_ = win / 25, wt = win % 25;
                    int i = (wt / 5) * 14 + p, j = (wt % 5) * 14 + q;
                    if (i < 64 && j < 64) {
                        size_t idx = (((size_t)b_ * 64 + i) * 64 + j) * 768 + gn;
                        ((float*)CoutV)[idx] = resid[idx] + v;
                    }
                } else if (EPI == 2) {
                    float gl = 0.5f * v * (1.0f + erff(v * 0.70710678118654752f));
                    ((u16*)CoutV)[(size_t)row * N + gn] = f2b(gl);
                } else {
                    size_t idx = (size_t)(row_base + row) * 768 + gn;
                    ((float*)CoutV)[idx] = resid[idx] + v;
                }
            }
        }
    }
}

// ---------------------------------------------------------------- attention v5
// (unchanged from R8 — verified passing)
#define AT_W 72
#define PB_W 40

__global__ __launch_bounds__(256) void attn_mfma(
    const u16* __restrict__ qkv,          // [nw*196][2304] = [..][3][12][64]
    const float* __restrict__ relh, const float* __restrict__ relw, // [27][64]
    u16* __restrict__ out)                // [nw*196][768]
{
    __shared__ __align__(16) u16 pbuf[4][32 * PB_W];     // 10240 B (rel_ext alias)
    __shared__ __align__(16) u16 Kc[64 * AT_W];          //  9216 B
    __shared__ __align__(16) u16 Vt[64 * AT_W];          //  9216 B
    u16* rel_ext = &pbuf[0][0];                          // 128*32*2 = 8192 B

    const int nwg = gridDim.x;
    const int swzb = xcd_swz(blockIdx.x, nwg);
    const int win = swzb / 24, rem = swzb % 24;
    const int head = rem >> 1, half = rem & 1;
    const int row0 = half * 128;
    const int tid = threadIdx.x, lane = tid & 63, wave = tid >> 6;
    const int quad = lane >> 4, l16 = lane & 15;
    const size_t base = (size_t)win * 196 * 2304 + (size_t)head * 64;

    short8 qf[2][2];
#pragma unroll
    for (int mi = 0; mi < 2; mi++) {
        int tok = row0 + wave * 32 + mi * 16 + l16;
        int rt = tok < 196 ? tok : 195;
        const u16* qp = qkv + base + (size_t)rt * 2304 + quad * 8;
        qf[mi][0] = *(const short8*)(qp);
        qf[mi][1] = *(const short8*)(qp + 32);
    }

    for (int e = tid; e < 64 * 64; e += 256) {
        int rr = e >> 6, cc = e & 63;
        float v = 0.f;
        if (rr < 27)      v = 8.f * relh[rr * 64 + cc];
        else if (rr < 54) v = 8.f * relw[(rr - 27) * 64 + cc];
        Kc[rr * AT_W + cc] = f2b(v);
    }
    if (tid < 128) {
        u16* rp = rel_ext + tid * 32;
        uint4 z = make_uint4(0u, 0u, 0u, 0u);
        *(uint4*)(rp) = z; *(uint4*)(rp + 8) = z;
        *(uint4*)(rp + 16) = z; *(uint4*)(rp + 24) = z;
        rp[31] = f2b(-1e30f);
    }
    __syncthreads();

#pragma unroll
    for (int cb = 0; cb < 2; cb++) {
#pragma unroll
        for (int nt = 0; nt < 2; nt++) {
            const u16* kp_ = Kc + (cb * 32 + nt * 16 + l16) * AT_W + quad * 8;
            short8 b0 = *(const short8*)(kp_);
            short8 b1 = *(const short8*)(kp_ + 32);
            int i = cb * 32 + nt * 16 + l16;
#pragma unroll
            for (int mi = 0; mi < 2; mi++) {
                f32x4 c = {};
                c = __builtin_amdgcn_mfma_f32_16x16x32_bf16(qf[mi][0], b0, c, 0, 0, 0);
                c = __builtin_amdgcn_mfma_f32_16x16x32_bf16(qf[mi][1], b1, c, 0, 0, 0);
#pragma unroll
                for (int r = 0; r < 4; r++) {
                    int row = wave * 32 + mi * 16 + quad * 4 + r;
                    int grow = row0 + row;
                    int rowB = grow < 196 ? grow : 195;
                    int p = rowB / 14, qq = rowB % 14;
                    if (i < 27) {
                        int t = p + 13 - i;
                        if (t >= 0 && t < 14) rel_ext[row * 32 + t] = f2b(c[r]);
                    } else if (i < 54) {
                        int t = qq + 13 - (i - 27);
                        if (t >= 0 && t < 14) rel_ext[row * 32 + 14 + t] = f2b(c[r]);
                    }
                }
            }
        }
    }
    short8 qe[2];
#pragma unroll
    for (int mi = 0; mi < 2; mi++)
        qe[mi] = *(const short8*)(rel_ext + (wave * 32 + mi * 16 + l16) * 32 + quad * 8);

    f32x4 acc[2][4] = {};
    float ml_[2][4], ll_[2][4];
#pragma unroll
    for (int mi = 0; mi < 2; mi++)
#pragma unroll
        for (int r = 0; r < 4; r++) { ml_[mi][r] = -1e30f; ll_[mi][r] = 0.f; }

#pragma unroll 1
    for (int c = 0; c < 4; c++) {
        const int kbase = c * 64;
        __syncthreads();
        {
            int key = tid >> 2;
            int cg  = (tid & 3) << 4;
            int gk = kbase + key;
            uint4 k0 = make_uint4(0u,0u,0u,0u), k1 = k0, v0 = k0, v1 = k0;
            if (gk < 196) {
                const u16* kp_ = qkv + base + 768  + (size_t)gk * 2304 + cg;
                const u16* vp_ = qkv + base + 1536 + (size_t)gk * 2304 + cg;
                k0 = *(const uint4*)(kp_); k1 = *(const uint4*)(kp_ + 8);
                v0 = *(const uint4*)(vp_); v1 = *(const uint4*)(vp_ + 8);
            }
            *(uint4*)(Kc + key * AT_W + cg)     = k0;
            *(uint4*)(Kc + key * AT_W + cg + 8) = k1;
            union { uint4 u; u16 h[8]; } a, b; a.u = v0; b.u = v1;
#pragma unroll
            for (int i = 0; i < 8; i++) Vt[(cg + i) * AT_W + key] = a.h[i];
#pragma unroll
            for (int i = 0; i < 8; i++) Vt[(cg + 8 + i) * AT_W + key] = b.h[i];
        }
        __syncthreads();

        short8 bo[4];
        {
            const u16 one = 0x3F80;
#pragma unroll
            for (int nt = 0; nt < 4; nt++) {
                int key = kbase + nt * 16 + l16;
                int inval = key >= 196;
                int kp = key / 14, kq = key - kp * 14;
                union { short8 s; u16 h[8]; } u;
#pragma unroll
                for (int j = 0; j < 8; j++) {
                    int t = quad * 8 + j;
                    u16 v = 0;
                    if (!inval && t == kp) v = one;
                    if (!inval && t >= 14 && (t - 14) == kq) v = one;
                    if (inval && t == 31) v = one;
                    u.h[j] = v;
                }
                bo[nt] = u.s;
            }
        }

        f32x4 s23[2][2];
#pragma unroll
        for (int mi = 0; mi < 2; mi++) {
            f32x4 s[4];
            __builtin_amdgcn_s_setprio(1);
#pragma unroll
            for (int nt = 0; nt < 4; nt++) {
                const u16* kp_ = Kc + (nt * 16 + l16) * AT_W + quad * 8;
                short8 kf0 = *(const short8*)(kp_);
                short8 kf1 = *(const short8*)(kp_ + 32);
                f32x4 t = {};
                t = __builtin_amdgcn_mfma_f32_16x16x32_bf16(qf[mi][0], kf0, t, 0, 0, 0);
                t = __builtin_amdgcn_mfma_f32_16x16x32_bf16(qf[mi][1], kf1, t, 0, 0, 0);
                t = __builtin_amdgcn_mfma_f32_16x16x32_bf16(qe[mi],    bo[nt], t, 0, 0, 0);
                s[nt] = t * 0.125f;
            }
            __builtin_amdgcn_s_setprio(0);
#pragma unroll
            for (int r = 0; r < 4; r++) {
                float mx = fmaxf(fmaxf(s[0][r], s[1][r]), fmaxf(s[2][r], s[3][r]));
#pragma unroll
                for (int off = 8; off; off >>= 1) mx = fmaxf(mx, __shfl_xor(mx, off, 16));
                float mo = ml_[mi][r];
                float mn = fmaxf(mo, mx);
                float alpha = __expf(mo - mn);
                ml_[mi][r] = mn;
                float p0 = __expf(s[0][r] - mn), p1 = __expf(s[1][r] - mn);
                float p2 = __expf(s[2][r] - mn), p3 = __expf(s[3][r] - mn);
                float ps = (p0 + p1) + (p2 + p3);
#pragma unroll
                for (int off = 8; off; off >>= 1) ps += __shfl_xor(ps, off, 16);
                ll_[mi][r] = ll_[mi][r] * alpha + ps;
#pragma unroll
                for (int ni = 0; ni < 4; ni++) acc[mi][ni][r] *= alpha;
                s[0][r] = p0; s[1][r] = p1; s[2][r] = p2; s[3][r] = p3;
            }
#pragma unroll
            for (int nt = 0; nt < 2; nt++)
#pragma unroll
                for (int r = 0; r < 4; r++)
                    pbuf[wave][(mi * 16 + quad * 4 + r) * PB_W + nt * 16 + l16] = f2b(s[nt][r]);
            s23[mi][0] = s[2]; s23[mi][1] = s[3];
        }

        __builtin_amdgcn_s_setprio(1);
#pragma unroll
        for (int mi = 0; mi < 2; mi++) {
            short8 pf = *(const short8*)(pbuf[wave] + (mi * 16 + l16) * PB_W + quad * 8);
#pragma unroll
            for (int ni = 0; ni < 4; ni++) {
                short8 vfn = *(const short8*)(Vt + (ni * 16 + l16) * AT_W + quad * 8);
                acc[mi][ni] = __builtin_amdgcn_mfma_f32_16x16x32_bf16(pf, vfn, acc[mi][ni], 0, 0, 0);
            }
        }
        __builtin_amdgcn_s_setprio(0);
#pragma unroll
        for (int mi = 0; mi < 2; mi++)
#pragma unroll
            for (int h = 0; h < 2; h++)
#pragma unroll
                for (int r = 0; r < 4; r++)
                    pbuf[wave][(mi * 16 + quad * 4 + r) * PB_W + h * 16 + l16] = f2b(s23[mi][h][r]);
        __builtin_amdgcn_s_setprio(1);
#pragma unroll
        for (int mi = 0; mi < 2; mi++) {
            short8 pf = *(const short8*)(pbuf[wave] + (mi * 16 + l16) * PB_W + quad * 8);
#pragma unroll
            for (int ni = 0; ni < 4; ni++) {
                short8 vfn = *(const short8*)(Vt + (ni * 16 + l16) * AT_W + 32 + quad * 8);
                acc[mi][ni] = __builtin_amdgcn_mfma_f32_16x16x32_bf16(pf, vfn, acc[mi][ni], 0, 0, 0);
            }
        }
        __builtin_amdgcn_s_setprio(0);
    }

#pragma unroll
    for (int mi = 0; mi < 2; mi++)
#pragma unroll
        for (int r = 0; r < 4; r++) {
            int tok = row0 + wave * 32 + mi * 16 + quad * 4 + r;
            if (tok < 196) {
                float inv = 1.f / ll_[mi][r];
                size_t ob = (size_t)(win * 196 + tok) * 768 + head * 64;
#pragma unroll
                for (int ni = 0; ni < 4; ni++)
                    out[ob + ni * 16 + l16] = f2b(acc[mi][ni][r] * inv);
            }
        }
}

// ---------------------------------------------------------------- launch
extern "C" void kernel_launch(void* const* d_in, const int* in_sizes, int n_in,
                              void* d_out, int out_size, void* d_ws, size_t ws_size,
                              hipStream_t stream)
{
    const float* x      = (const float*)d_in[0];
    const float* g1     = (const float*)d_in[1];
    const float* beta1  = (const float*)d_in[2];
    const float* w_qkv  = (const float*)d_in[3];
    const float* b_qkv  = (const float*)d_in[4];
    const float* w_proj = (const float*)d_in[5];
    const float* b_proj = (const float*)d_in[6];
    const float* rph    = (const float*)d_in[7];
    const float* rpw    = (const float*)d_in[8];
    const float* g2     = (const float*)d_in[9];
    const float* beta2  = (const float*)d_in[10];
    const float* w_fc1  = (const float*)d_in[11];
    const float* b_fc1  = (const float*)d_in[12];
    const float* w_fc2  = (const float*)d_in[13];
    const float* b_fc2  = (const float*)d_in[14];
    float* out = (float*)d_out;

    const size_t WT = 14155776;
    size_t b1 = 0, b2 = 0;
    int nc = 0, mc = 0;
    auto fits = [&](int a, int m) -> bool {
        size_t rows = (size_t)(200 / a) * 196, toks = (size_t)32768 / m;
        size_t bb1 = rows * 768 * 2 >= toks * 768 * 2 ? rows * 768 * 2 : toks * 768 * 2;
        size_t bb2 = rows * 2304 * 2 >= toks * 3072 * 2 ? rows * 2304 * 2 : toks * 3072 * 2;
        if (WT + bb1 + bb2 <= ws_size) { b1 = bb1; b2 = bb2; nc = a; mc = m; return true; }
        return false;
    };
    if (!fits(1, 1) && !fits(1, 2) && !fits(2, 2) && !fits(2, 4) && !fits(4, 4))
        return;   // diagnostic: leaves d_out untouched

    char* ws = (char*)d_ws;
    u16* wt0 = (u16*)ws;                               // qkv^T  2304x768
    u16* wt1 = wt0 + 2304 * 768;                       // proj^T  768x768
    u16* wt2 = wt1 + 768 * 768;                        // fc1^T  3072x768
    u16* wt3 = wt2 + 3072 * 768;                       // fc2^T   768x3072
    u16* buf1 = (u16*)(ws + WT);
    u16* buf2 = (u16*)(ws + WT + b1);

    dim3 blk(256), blk5(512);

    transpose_k<<<(768/32)*(2304/32), blk, 0, stream>>>(w_qkv,  wt0, 768, 2304);
    transpose_k<<<(768/32)*(768/32),  blk, 0, stream>>>(w_proj, wt1, 768, 768);
    transpose_k<<<(768/32)*(3072/32), blk, 0, stream>>>(w_fc1,  wt2, 768, 3072);
    transpose_k<<<(3072/32)*(768/32), blk, 0, stream>>>(w_fc2,  wt3, 3072, 768);

    // ---- attention phase: nc chunks of (200/nc) windows ----
    {
        const int nw = 200 / nc, rows = nw * 196;
        const int mt = (rows + 255) / 256;
        for (int c = 0; c < nc; c++) {
            const int rb = c * rows;
            ln_kernel<<<rows, blk, 0, stream>>>(x, g1, beta1, buf1, 1, rb);
            gemm256<0><<<dim3(mt * (2304/256)), blk5, 0, stream>>>(
                buf1, wt0, b_qkv, buf2, nullptr, rows, 2304, 768, 0);
            attn_mfma<<<nw * 24, blk, 0, stream>>>(buf2, rph, rpw, buf1);
            gemm256<1><<<dim3(mt * (768/256)), blk5, 0, stream>>>(
                buf1, wt1, b_proj, out, x, rows, 768, 768, rb);
        }
    }

    // ---- MLP phase: mc chunks of (32768/mc) tokens ----
    {
        const int tk = 32768 / mc;
        const int mt2 = (tk + 255) / 256;
        for (int c = 0; c < mc; c++) {
            const int rb = c * tk;
            ln_kernel<<<tk, blk, 0, stream>>>(
                out + (size_t)rb * 768, g2, beta2, buf1, 0, 0);
            gemm256<2><<<dim3(mt2 * (3072/256)), blk5, 0, stream>>>(
                buf1, wt2, b_fc1, buf2, nullptr, tk, 3072, 768, 0);
            gemm256<3><<<dim3(mt2 * (768/256)), blk5, 0, stream>>>(
                buf2, wt3, b_fc2, out, out, tk, 768, 3072, rb);
        }
    }
}

// Round 7
// 1533.202 us; speedup vs baseline: 1.0172x; 1.0100x over previous
//
#include <hip/hip_runtime.h>
#include <cstdint>

// Block_32401233281211: SAM-style windowed-attention transformer block.
// I/O dtype: FLOAT32. Internal GEMMs + attention: bf16 MFMA.
// B=8, H=W=64, C=768, heads=12, hd=64, FF=3072, WS=14 -> pad to 70x70,
// 200 windows x 196 tokens = 39200 window-token rows.
// R8: attention half-blocks (~200us, kept).
// R9-R12 lesson: every coarse stage/wait/read-burst/MFMA-burst schedule pins
//   MfmaUtil at 18-19% (5600 cyc per K-tile vs 1030 of MFMA). The m201-style
//   FINE interleave (16 MFMA + few ds_reads + 1 stage per barrier-pair,
//   counted vmcnt once per K-tile) reaches 62% on identical data flow.
// R13 (this round): 8-phase-style fine interleave, tri-buffered:
//   - 256x256 tile, BK=32, 2 phases/K-tile; per phase: {<=8 ds_read_b128,
//     2 gload_lds (one half of tile t+2), barrier, lgkmcnt(0), setprio,
//     16 MFMA, setprio, barrier}
//   - tri-buffer (6 static 16KB arrays, 96KB), stage leads reads by 2 K-tiles
//   - vmcnt(4) once per K-tile: retires exactly tile t+1, keeps t+2 in flight
//     (ledger: P0(t) stages A(t+2), P1(t) stages B(t+2); outstanding at
//     P1(t) = 8; vmcnt(4) -> tile t+1 landed before its reads)
//   - swizzle/staging/epilogue identical to R12 (HW-verified, 0 conflicts)

typedef unsigned short u16;
typedef __attribute__((ext_vector_type(8))) short short8;   // 8 x bf16
typedef __attribute__((ext_vector_type(4))) float f32x4;

__device__ __forceinline__ u16 f2b(float f) {
    union { float f; unsigned int i; } x; x.f = f;
    unsigned int u = x.i;
    return (u16)((u + 0x7fffu + ((u >> 16) & 1u)) >> 16);   // RNE
}
__device__ __forceinline__ float b2f(u16 u) {
    union { unsigned int i; float f; } x; x.i = ((unsigned int)u) << 16; return x.f;
}

// async global->LDS, 16 B per lane. LDS dest = wave-uniform base + lane*16.
__device__ __forceinline__ void gload16(const u16* g, u16* l) {
    __builtin_amdgcn_global_load_lds(
        (const __attribute__((address_space(1))) unsigned int*)g,
        (__attribute__((address_space(3))) unsigned int*)l, 16, 0, 0);
}

// bijective XCD swizzle (m204)
__device__ __forceinline__ int xcd_swz(int bid, int nwg) {
    int q = nwg >> 3, r = nwg & 7;
    int x = bid & 7, lo = bid >> 3;
    return (x < r ? x * (q + 1) : r * (q + 1) + (x - r) * q) + lo;
}

// ---------------------------------------------------------------- transpose
__global__ __launch_bounds__(256) void transpose_k(
    const float* __restrict__ in, u16* __restrict__ out, int R, int C)
{
    __shared__ float tile[32][33];
    int bpc = C >> 5;
    int r0 = (blockIdx.x / bpc) << 5;
    int c0 = (blockIdx.x % bpc) << 5;
    int lx = threadIdx.x & 31, ly = threadIdx.x >> 5;
#pragma unroll
    for (int s = 0; s < 32; s += 8)
        tile[ly + s][lx] = in[(size_t)(r0 + ly + s) * C + c0 + lx];
    __syncthreads();
#pragma unroll
    for (int s = 0; s < 32; s += 8)
        out[(size_t)(c0 + ly + s) * R + r0 + lx] = f2b(tile[lx][ly + s]);
}

// ---------------------------------------------------------------- layernorm
__global__ __launch_bounds__(256) void ln_kernel(
    const float* __restrict__ in, const float* __restrict__ g,
    const float* __restrict__ beta, u16* __restrict__ out, int windowed,
    int row_base)
{
    __shared__ float sbuf[4];
    int tid = threadIdx.x;
    size_t orow = (size_t)blockIdx.x * 768;
    size_t irow;
    if (windowed) {
        int r = row_base + blockIdx.x;
        int win = r / 196, t = r % 196;
        int p = t / 14, q = t % 14;
        int b = win / 25, wt = win % 25;
        int i = (wt / 5) * 14 + p, j = (wt % 5) * 14 + q;
        if (i >= 64 || j >= 64) {
            out[orow + tid] = 0; out[orow + tid + 256] = 0; out[orow + tid + 512] = 0;
            return;
        }
        irow = (((size_t)b * 64 + i) * 64 + j) * 768;
    } else {
        irow = (size_t)blockIdx.x * 768;
    }
    float v0 = in[irow + tid];
    float v1 = in[irow + tid + 256];
    float v2 = in[irow + tid + 512];
    float s = v0 + v1 + v2;
#pragma unroll
    for (int off = 32; off; off >>= 1) s += __shfl_xor(s, off, 64);
    if ((tid & 63) == 0) sbuf[tid >> 6] = s;
    __syncthreads();
    float mean = (sbuf[0] + sbuf[1] + sbuf[2] + sbuf[3]) * (1.f / 768.f);
    __syncthreads();
    float d0 = v0 - mean, d1 = v1 - mean, d2 = v2 - mean;
    float sq = d0 * d0 + d1 * d1 + d2 * d2;
#pragma unroll
    for (int off = 32; off; off >>= 1) sq += __shfl_xor(sq, off, 64);
    if ((tid & 63) == 0) sbuf[tid >> 6] = sq;
    __syncthreads();
    float var = (sbuf[0] + sbuf[1] + sbuf[2] + sbuf[3]) * (1.f / 768.f);
    float rs = rsqrtf(var + 1e-6f);
    out[orow + tid]       = f2b(d0 * rs * g[tid]       + beta[tid]);
    out[orow + tid + 256] = f2b(d1 * rs * g[tid + 256] + beta[tid + 256]);
    out[orow + tid + 512] = f2b(d2 * rs * g[tid + 512] + beta[tid + 512]);
}

// ---------------------------------------------------------------- GEMM 256x256
// C(MxN) = A(MxK) @ Bt(NxK)^T + bias, bf16 in / f32 acc, MFMA 16x16x32.
// 512 threads = 8 waves (2M x 4N); wave tile 128x64 = acc[8][4]. BK=32.
// Tri-buffer: tile t -> buf t%3 (As0..2/Bs0..2, 16 KB each, 96 KB total);
// main loop unrolled x3 so all LDS indexing is compile-time.
// Panel = 256 rows x 32 elems (64 B rows); swizzle: row r holds k-chunk kc at
// chunk kc ^ ((r>>1)&3); staged via inverse-permuted global source
// (involution; HW-verified R12, 0 bank conflicts).
// Per K-tile t (2 phases):
//  P0: ds_read a(m0-3),b(n0-3) | gload A(t+2) | bar | lgkm0 | 16 MFMA | bar
//  P1: ds_read a(m4-7)         | gload B(t+2) | vmcnt(4) | bar | lgkm0
//      | 16 MFMA | bar
// vmcnt(4): outstanding = tile t+1 (4) + tile t+2 (4, just issued) -> retires
// exactly tile t+1 before any wave reads it; never drains to 0 in main loop.
// Requires K % 96 == 0 (nt = K/32 divisible by 3): K=768 (24), K=3072 (96).
// Tail M-rows stage garbage (land in adjacent workspace); epilogue skips.

__device__ __forceinline__ short8 ldsf(const u16* P, int r, int quad) {
    return *(const short8*)(P + r * 32 + ((quad ^ ((r >> 1) & 3)) << 3));
}

#define MF(I, J, AA, BB) \
    acc[I][J] = __builtin_amdgcn_mfma_f32_16x16x32_bf16(AA, BB, acc[I][J], 0, 0, 0)

#define STAGE_A(SA, TT) {                                                   \
        const size_t kk = (size_t)((TT) << 5);                              \
        gload16(A + aoff0 + kk, (SA) + wbase);                              \
        gload16(A + aoff1 + kk, (SA) + 4096 + wbase); }

#define STAGE_B(SB, TT) {                                                   \
        const size_t kk = (size_t)((TT) << 5);                              \
        gload16(Bt + boff0 + kk, (SB) + wbase);                             \
        gload16(Bt + boff1 + kk, (SB) + 4096 + wbase); }

#define TILE(CA, CB, SA, SB, TT)                                            \
    {                                                                       \
        /* ---- phase 0 ---- */                                             \
        short8 a0_ = ldsf(CA, wr128 + l16,       quad);                     \
        short8 a1_ = ldsf(CA, wr128 + 16 + l16,  quad);                     \
        short8 a2_ = ldsf(CA, wr128 + 32 + l16,  quad);                     \
        short8 a3_ = ldsf(CA, wr128 + 48 + l16,  quad);                     \
        short8 b0_ = ldsf(CB, wc64 + l16,        quad);                     \
        short8 b1_ = ldsf(CB, wc64 + 16 + l16,   quad);                     \
        short8 b2_ = ldsf(CB, wc64 + 32 + l16,   quad);                     \
        short8 b3_ = ldsf(CB, wc64 + 48 + l16,   quad);                     \
        if ((TT) + 2 < nt) STAGE_A(SA, (TT) + 2);                           \
        __builtin_amdgcn_sched_barrier(0);                                  \
        __builtin_amdgcn_s_barrier();                                       \
        __builtin_amdgcn_sched_barrier(0);                                  \
        asm volatile("s_waitcnt lgkmcnt(0)" ::: "memory");                  \
        __builtin_amdgcn_sched_barrier(0);                                  \
        __builtin_amdgcn_s_setprio(1);                                      \
        MF(0,0,a0_,b0_); MF(1,0,a1_,b0_); MF(2,0,a2_,b0_); MF(3,0,a3_,b0_); \
        MF(0,1,a0_,b1_); MF(1,1,a1_,b1_); MF(2,1,a2_,b1_); MF(3,1,a3_,b1_); \
        MF(0,2,a0_,b2_); MF(1,2,a1_,b2_); MF(2,2,a2_,b2_); MF(3,2,a3_,b2_); \
        MF(0,3,a0_,b3_); MF(1,3,a1_,b3_); MF(2,3,a2_,b3_); MF(3,3,a3_,b3_); \
        __builtin_amdgcn_s_setprio(0);                                      \
        __builtin_amdgcn_sched_barrier(0);                                  \
        __builtin_amdgcn_s_barrier();                                       \
        __builtin_amdgcn_sched_barrier(0);                                  \
        /* ---- phase 1 ---- */                                             \
        a0_ = ldsf(CA, wr128 + 64 + l16,  quad);                            \
        a1_ = ldsf(CA, wr128 + 80 + l16,  quad);                            \
        a2_ = ldsf(CA, wr128 + 96 + l16,  quad);                            \
        a3_ = ldsf(CA, wr128 + 112 + l16, quad);                            \
        if ((TT) + 2 < nt) STAGE_B(SB, (TT) + 2);                           \
        __builtin_amdgcn_sched_barrier(0);                                  \
        if ((TT) + 2 < nt) {                                                \
            asm volatile("s_waitcnt vmcnt(4)" ::: "memory");                \
        } else if ((TT) + 1 < nt) {                                         \
            asm volatile("s_waitcnt vmcnt(0)" ::: "memory");                \
        }                                                                   \
        __builtin_amdgcn_sched_barrier(0);                                  \
        __builtin_amdgcn_s_barrier();                                       \
        __builtin_amdgcn_sched_barrier(0);                                  \
        asm volatile("s_waitcnt lgkmcnt(0)" ::: "memory");                  \
        __builtin_amdgcn_sched_barrier(0);                                  \
        __builtin_amdgcn_s_setprio(1);                                      \
        MF(4,0,a0_,b0_); MF(5,0,a1_,b0_); MF(6,0,a2_,b0_); MF(7,0,a3_,b0_); \
        MF(4,1,a0_,b1_); MF(5,1,a1_,b1_); MF(6,1,a2_,b1_); MF(7,1,a3_,b1_); \
        MF(4,2,a0_,b2_); MF(5,2,a1_,b2_); MF(6,2,a2_,b2_); MF(7,2,a3_,b2_); \
        MF(4,3,a0_,b3_); MF(5,3,a1_,b3_); MF(6,3,a2_,b3_); MF(7,3,a3_,b3_); \
        __builtin_amdgcn_s_setprio(0);                                      \
        __builtin_amdgcn_sched_barrier(0);                                  \
        __builtin_amdgcn_s_barrier();                                       \
        __builtin_amdgcn_sched_barrier(0);                                  \
    }

template <int EPI>
__global__ __launch_bounds__(512) void gemm256(
    const u16* __restrict__ A, const u16* __restrict__ Bt,
    const float* __restrict__ bias, void* __restrict__ CoutV,
    const float* __restrict__ resid, int M, int N, int K, int row_base)
{
    __shared__ __align__(16) u16 As0[256 * 32];
    __shared__ __align__(16) u16 As1[256 * 32];
    __shared__ __align__(16) u16 As2[256 * 32];
    __shared__ __align__(16) u16 Bs0[256 * 32];
    __shared__ __align__(16) u16 Bs1[256 * 32];
    __shared__ __align__(16) u16 Bs2[256 * 32];

    const int tid = threadIdx.x;
    const int lane = tid & 63, wave = tid >> 6;        // 8 waves
    const int wr = wave >> 2, wc = wave & 3;           // 2 x 4
    const int quad = lane >> 4, l16 = lane & 15;
    const int wr128 = wr * 128, wc64 = wc * 64;
    const int ntile = N / 256;
    const int swz = xcd_swz(blockIdx.x, gridDim.x);
    const int m0 = (swz / ntile) * 256;
    const int n0 = (swz % ntile) * 256;

    // staging lane constants (swizzle involution; HW-verified R12)
    const int rA   = (wave << 4) + (lane >> 2);        // panel row 0..127
    const int kcol = (((lane & 3) ^ ((rA >> 1) & 3)) << 3);
    const size_t aoff0 = (size_t)(m0 + rA) * K + kcol;
    const size_t aoff1 = aoff0 + (size_t)128 * K;
    const size_t boff0 = (size_t)(n0 + rA) * K + kcol;
    const size_t boff1 = boff0 + (size_t)128 * K;
    const int wbase = wave * 512;                      // wave-uniform LDS base

    f32x4 acc[8][4] = {};
    const int nt = K >> 5;                             // K/32, divisible by 3

    // prologue: stage tiles 0 and 1; wait tile 0
    STAGE_A(As0, 0); STAGE_B(Bs0, 0);
    STAGE_A(As1, 1); STAGE_B(Bs1, 1);
    __builtin_amdgcn_sched_barrier(0);
    asm volatile("s_waitcnt vmcnt(4)" ::: "memory");   // tile 0 landed
    __builtin_amdgcn_sched_barrier(0);
    __builtin_amdgcn_s_barrier();
    __builtin_amdgcn_sched_barrier(0);

#pragma unroll 1
    for (int t = 0; t < nt; t += 3) {
        TILE(As0, Bs0, As2, Bs2, t);        // read buf0, stage t+2 -> buf2
        TILE(As1, Bs1, As0, Bs0, t + 1);    // read buf1, stage t+3 -> buf0
        TILE(As2, Bs2, As1, Bs1, t + 2);    // read buf2, stage t+4 -> buf1
    }

    // ---- epilogue
#pragma unroll
    for (int mi = 0; mi < 8; mi++) {
#pragma unroll
        for (int ni = 0; ni < 4; ni++) {
            const int gn = n0 + wc * 64 + ni * 16 + l16;
            const float bv = bias[gn];
#pragma unroll
            for (int r = 0; r < 4; r++) {
                const int row = m0 + wr * 128 + mi * 16 + quad * 4 + r;
                if (row >= M) continue;
                float v = acc[mi][ni][r] + bv;
                if (EPI == 0) {
                    ((u16*)CoutV)[(size_t)row * N + gn] = f2b(v);
                } else if (EPI == 1) {
                    int grow = row_base + row;
                    int win = grow / 196, t = grow % 196;
                    int p = t / 14, q = t % 14;
                    int b_ = win / 25, wt = win % 25;
                    int i = (wt / 5) * 14 + p, j = (wt % 5) * 14 + q;
                    if (i < 64 && j < 64) {
                        size_t idx = (((size_t)b_ * 64 + i) * 64 + j) * 768 + gn;
                        ((float*)CoutV)[idx] = resid[idx] + v;
                    }
                } else if (EPI == 2) {
                    float gl = 0.5f * v * (1.0f + erff(v * 0.70710678118654752f));
                    ((u16*)CoutV)[(size_t)row * N + gn] = f2b(gl);
                } else {
                    size_t idx = (size_t)(row_base + row) * 768 + gn;
                    ((float*)CoutV)[idx] = resid[idx] + v;
                }
            }
        }
    }
}

// ---------------------------------------------------------------- attention v5
// (unchanged from R8 — verified passing)
#define AT_W 72
#define PB_W 40

__global__ __launch_bounds__(256) void attn_mfma(
    const u16* __restrict__ qkv,          // [nw*196][2304] = [..][3][12][64]
    const float* __restrict__ relh, const float* __restrict__ relw, // [27][64]
    u16* __restrict__ out)                // [nw*196][768]
{
    __shared__ __align__(16) u16 pbuf[4][32 * PB_W];     // 10240 B (rel_ext alias)
    __shared__ __align__(16) u16 Kc[64 * AT_W];          //  9216 B
    __shared__ __align__(16) u16 Vt[64 * AT_W];          //  9216 B
    u16* rel_ext = &pbuf[0][0];                          // 128*32*2 = 8192 B

    const int nwg = gridDim.x;
    const int swzb = xcd_swz(blockIdx.x, nwg);
    const int win = swzb / 24, rem = swzb % 24;
    const int head = rem >> 1, half = rem & 1;
    const int row0 = half * 128;
    const int tid = threadIdx.x, lane = tid & 63, wave = tid >> 6;
    const int quad = lane >> 4, l16 = lane & 15;
    const size_t base = (size_t)win * 196 * 2304 + (size_t)head * 64;

    short8 qf[2][2];
#pragma unroll
    for (int mi = 0; mi < 2; mi++) {
        int tok = row0 + wave * 32 + mi * 16 + l16;
        int rt = tok < 196 ? tok : 195;
        const u16* qp = qkv + base + (size_t)rt * 2304 + quad * 8;
        qf[mi][0] = *(const short8*)(qp);
        qf[mi][1] = *(const short8*)(qp + 32);
    }

    for (int e = tid; e < 64 * 64; e += 256) {
        int rr = e >> 6, cc = e & 63;
        float v = 0.f;
        if (rr < 27)      v = 8.f * relh[rr * 64 + cc];
        else if (rr < 54) v = 8.f * relw[(rr - 27) * 64 + cc];
        Kc[rr * AT_W + cc] = f2b(v);
    }
    if (tid < 128) {
        u16* rp = rel_ext + tid * 32;
        uint4 z = make_uint4(0u, 0u, 0u, 0u);
        *(uint4*)(rp) = z; *(uint4*)(rp + 8) = z;
        *(uint4*)(rp + 16) = z; *(uint4*)(rp + 24) = z;
        rp[31] = f2b(-1e30f);
    }
    __syncthreads();

#pragma unroll
    for (int cb = 0; cb < 2; cb++) {
#pragma unroll
        for (int nt = 0; nt < 2; nt++) {
            const u16* kp_ = Kc + (cb * 32 + nt * 16 + l16) * AT_W + quad * 8;
            short8 b0 = *(const short8*)(kp_);
            short8 b1 = *(const short8*)(kp_ + 32);
            int i = cb * 32 + nt * 16 + l16;
#pragma unroll
            for (int mi = 0; mi < 2; mi++) {
                f32x4 c = {};
                c = __builtin_amdgcn_mfma_f32_16x16x32_bf16(qf[mi][0], b0, c, 0, 0, 0);
                c = __builtin_amdgcn_mfma_f32_16x16x32_bf16(qf[mi][1], b1, c, 0, 0, 0);
#pragma unroll
                for (int r = 0; r < 4; r++) {
                    int row = wave * 32 + mi * 16 + quad * 4 + r;
                    int grow = row0 + row;
                    int rowB = grow < 196 ? grow : 195;
                    int p = rowB / 14, qq = rowB % 14;
                    if (i < 27) {
                        int t = p + 13 - i;
                        if (t >= 0 && t < 14) rel_ext[row * 32 + t] = f2b(c[r]);
                    } else if (i < 54) {
                        int t = qq + 13 - (i - 27);
                        if (t >= 0 && t < 14) rel_ext[row * 32 + 14 + t] = f2b(c[r]);
                    }
                }
            }
        }
    }
    short8 qe[2];
#pragma unroll
    for (int mi = 0; mi < 2; mi++)
        qe[mi] = *(const short8*)(rel_ext + (wave * 32 + mi * 16 + l16) * 32 + quad * 8);

    f32x4 acc[2][4] = {};
    float ml_[2][4], ll_[2][4];
#pragma unroll
    for (int mi = 0; mi < 2; mi++)
#pragma unroll
        for (int r = 0; r < 4; r++) { ml_[mi][r] = -1e30f; ll_[mi][r] = 0.f; }

#pragma unroll 1
    for (int c = 0; c < 4; c++) {
        const int kbase = c * 64;
        __syncthreads();
        {
            int key = tid >> 2;
            int cg  = (tid & 3) << 4;
            int gk = kbase + key;
            uint4 k0 = make_uint4(0u,0u,0u,0u), k1 = k0, v0 = k0, v1 = k0;
            if (gk < 196) {
                const u16* kp_ = qkv + base + 768  + (size_t)gk * 2304 + cg;
                const u16* vp_ = qkv + base + 1536 + (size_t)gk * 2304 + cg;
                k0 = *(const uint4*)(kp_); k1 = *(const uint4*)(kp_ + 8);
                v0 = *(const uint4*)(vp_); v1 = *(const uint4*)(vp_ + 8);
            }
            *(uint4*)(Kc + key * AT_W + cg)     = k0;
            *(uint4*)(Kc + key * AT_W + cg + 8) = k1;
            union { uint4 u; u16 h[8]; } a, b; a.u = v0; b.u = v1;
#pragma unroll
            for (int i = 0; i < 8; i++) Vt[(cg + i) * AT_W + key] = a.h[i];
#pragma unroll
            for (int i = 0; i < 8; i++) Vt[(cg + 8 + i) * AT_W + key] = b.h[i];
        }
        __syncthreads();

        short8 bo[4];
        {
            const u16 one = 0x3F80;
#pragma unroll
            for (int nt = 0; nt < 4; nt++) {
                int key = kbase + nt * 16 + l16;
                int inval = key >= 196;
                int kp = key / 14, kq = key - kp * 14;
                union { short8 s; u16 h[8]; } u;
#pragma unroll
                for (int j = 0; j < 8; j++) {
                    int t = quad * 8 + j;
                    u16 v = 0;
                    if (!inval && t == kp) v = one;
                    if (!inval && t >= 14 && (t - 14) == kq) v = one;
                    if (inval && t == 31) v = one;
                    u.h[j] = v;
                }
                bo[nt] = u.s;
            }
        }

        f32x4 s23[2][2];
#pragma unroll
        for (int mi = 0; mi < 2; mi++) {
            f32x4 s[4];
            __builtin_amdgcn_s_setprio(1);
#pragma unroll
            for (int nt = 0; nt < 4; nt++) {
                const u16* kp_ = Kc + (nt * 16 + l16) * AT_W + quad * 8;
                short8 kf0 = *(const short8*)(kp_);
                short8 kf1 = *(const short8*)(kp_ + 32);
                f32x4 t = {};
                t = __builtin_amdgcn_mfma_f32_16x16x32_bf16(qf[mi][0], kf0, t, 0, 0, 0);
                t = __builtin_amdgcn_mfma_f32_16x16x32_bf16(qf[mi][1], kf1, t, 0, 0, 0);
                t = __builtin_amdgcn_mfma_f32_16x16x32_bf16(qe[mi],    bo[nt], t, 0, 0, 0);
                s[nt] = t * 0.125f;
            }
            __builtin_amdgcn_s_setprio(0);
#pragma unroll
            for (int r = 0; r < 4; r++) {
                float mx = fmaxf(fmaxf(s[0][r], s[1][r]), fmaxf(s[2][r], s[3][r]));
#pragma unroll
                for (int off = 8; off; off >>= 1) mx = fmaxf(mx, __shfl_xor(mx, off, 16));
                float mo = ml_[mi][r];
                float mn = fmaxf(mo, mx);
                float alpha = __expf(mo - mn);
                ml_[mi][r] = mn;
                float p0 = __expf(s[0][r] - mn), p1 = __expf(s[1][r] - mn);
                float p2 = __expf(s[2][r] - mn), p3 = __expf(s[3][r] - mn);
                float ps = (p0 + p1) + (p2 + p3);
#pragma unroll
                for (int off = 8; off; off >>= 1) ps += __shfl_xor(ps, off, 16);
                ll_[mi][r] = ll_[mi][r] * alpha + ps;
#pragma unroll
                for (int ni = 0; ni < 4; ni++) acc[mi][ni][r] *= alpha;
                s[0][r] = p0; s[1][r] = p1; s[2][r] = p2; s[3][r] = p3;
            }
#pragma unroll
            for (int nt = 0; nt < 2; nt++)
#pragma unroll
                for (int r = 0; r < 4; r++)
                    pbuf[wave][(mi * 16 + quad * 4 + r) * PB_W + nt * 16 + l16] = f2b(s[nt][r]);
            s23[mi][0] = s[2]; s23[mi][1] = s[3];
        }

        __builtin_amdgcn_s_setprio(1);
#pragma unroll
        for (int mi = 0; mi < 2; mi++) {
            short8 pf = *(const short8*)(pbuf[wave] + (mi * 16 + l16) * PB_W + quad * 8);
#pragma unroll
            for (int ni = 0; ni < 4; ni++) {
                short8 vfn = *(const short8*)(Vt + (ni * 16 + l16) * AT_W + quad * 8);
                acc[mi][ni] = __builtin_amdgcn_mfma_f32_16x16x32_bf16(pf, vfn, acc[mi][ni], 0, 0, 0);
            }
        }
        __builtin_amdgcn_s_setprio(0);
#pragma unroll
        for (int mi = 0; mi < 2; mi++)
#pragma unroll
            for (int h = 0; h < 2; h++)
#pragma unroll
                for (int r = 0; r < 4; r++)
                    pbuf[wave][(mi * 16 + quad * 4 + r) * PB_W + h * 16 + l16] = f2b(s23[mi][h][r]);
        __builtin_amdgcn_s_setprio(1);
#pragma unroll
        for (int mi = 0; mi < 2; mi++) {
            short8 pf = *(const short8*)(pbuf[wave] + (mi * 16 + l16) * PB_W + quad * 8);
#pragma unroll
            for (int ni = 0; ni < 4; ni++) {
                short8 vfn = *(const short8*)(Vt + (ni * 16 + l16) * AT_W + 32 + quad * 8);
                acc[mi][ni] = __builtin_amdgcn_mfma_f32_16x16x32_bf16(pf, vfn, acc[mi][ni], 0, 0, 0);
            }
        }
        __builtin_amdgcn_s_setprio(0);
    }

#pragma unroll
    for (int mi = 0; mi < 2; mi++)
#pragma unroll
        for (int r = 0; r < 4; r++) {
            int tok = row0 + wave * 32 + mi * 16 + quad * 4 + r;
            if (tok < 196) {
                float inv = 1.f / ll_[mi][r];
                size_t ob = (size_t)(win * 196 + tok) * 768 + head * 64;
#pragma unroll
                for (int ni = 0; ni < 4; ni++)
                    out[ob + ni * 16 + l16] = f2b(acc[mi][ni][r] * inv);
            }
        }
}

// ---------------------------------------------------------------- launch
extern "C" void kernel_launch(void* const* d_in, const int* in_sizes, int n_in,
                              void* d_out, int out_size, void* d_ws, size_t ws_size,
                              hipStream_t stream)
{
    const float* x      = (const float*)d_in[0];
    const float* g1     = (const float*)d_in[1];
    const float* beta1  = (const float*)d_in[2];
    const float* w_qkv  = (const float*)d_in[3];
    const float* b_qkv  = (const float*)d_in[4];
    const float* w_proj = (const float*)d_in[5];
    const float* b_proj = (const float*)d_in[6];
    const float* rph    = (const float*)d_in[7];
    const float* rpw    = (const float*)d_in[8];
    const float* g2     = (const float*)d_in[9];
    const float* beta2  = (const float*)d_in[10];
    const float* w_fc1  = (const float*)d_in[11];
    const float* b_fc1  = (const float*)d_in[12];
    const float* w_fc2  = (const float*)d_in[13];
    const float* b_fc2  = (const float*)d_in[14];
    float* out = (float*)d_out;

    const size_t WT = 14155776;
    size_t b1 = 0, b2 = 0;
    int nc = 0, mc = 0;
    auto fits = [&](int a, int m) -> bool {
        size_t rows = (size_t)(200 / a) * 196, toks = (size_t)32768 / m;
        size_t bb1 = rows * 768 * 2 >= toks * 768 * 2 ? rows * 768 * 2 : toks * 768 * 2;
        size_t bb2 = rows * 2304 * 2 >= toks * 3072 * 2 ? rows * 2304 * 2 : toks * 3072 * 2;
        if (WT + bb1 + bb2 <= ws_size) { b1 = bb1; b2 = bb2; nc = a; mc = m; return true; }
        return false;
    };
    if (!fits(1, 1) && !fits(1, 2) && !fits(2, 2) && !fits(2, 4) && !fits(4, 4))
        return;   // diagnostic: leaves d_out untouched

    char* ws = (char*)d_ws;
    u16* wt0 = (u16*)ws;                               // qkv^T  2304x768
    u16* wt1 = wt0 + 2304 * 768;                       // proj^T  768x768
    u16* wt2 = wt1 + 768 * 768;                        // fc1^T  3072x768
    u16* wt3 = wt2 + 3072 * 768;                       // fc2^T   768x3072
    u16* buf1 = (u16*)(ws + WT);
    u16* buf2 = (u16*)(ws + WT + b1);

    dim3 blk(256), blk5(512);

    transpose_k<<<(768/32)*(2304/32), blk, 0, stream>>>(w_qkv,  wt0, 768, 2304);
    transpose_k<<<(768/32)*(768/32),  blk, 0, stream>>>(w_proj, wt1, 768, 768);
    transpose_k<<<(768/32)*(3072/32), blk, 0, stream>>>(w_fc1,  wt2, 768, 3072);
    transpose_k<<<(3072/32)*(768/32), blk, 0, stream>>>(w_fc2,  wt3, 3072, 768);

    // ---- attention phase: nc chunks of (200/nc) windows ----
    {
        const int nw = 200 / nc, rows = nw * 196;
        const int mt = (rows + 255) / 256;
        for (int c = 0; c < nc; c++) {
            const int rb = c * rows;
            ln_kernel<<<rows, blk, 0, stream>>>(x, g1, beta1, buf1, 1, rb);
            gemm256<0><<<dim3(mt * (2304/256)), blk5, 0, stream>>>(
                buf1, wt0, b_qkv, buf2, nullptr, rows, 2304, 768, 0);
            attn_mfma<<<nw * 24, blk, 0, stream>>>(buf2, rph, rpw, buf1);
            gemm256<1><<<dim3(mt * (768/256)), blk5, 0, stream>>>(
                buf1, wt1, b_proj, out, x, rows, 768, 768, rb);
        }
    }

    // ---- MLP phase: mc chunks of (32768/mc) tokens ----
    {
        const int tk = 32768 / mc;
        const int mt2 = (tk + 255) / 256;
        for (int c = 0; c < mc; c++) {
            const int rb = c * tk;
            ln_kernel<<<tk, blk, 0, stream>>>(
                out + (size_t)rb * 768, g2, beta2, buf1, 0, 0);
            gemm256<2><<<dim3(mt2 * (3072/256)), blk5, 0, stream>>>(
                buf1, wt2, b_fc1, buf2, nullptr, tk, 3072, 768, 0);
            gemm256<3><<<dim3(mt2 * (768/256)), blk5, 0, stream>>>(
                buf2, wt3, b_fc2, out, out, tk, 768, 3072, rb);
        }
    }
}

// Round 8
// 1423.813 us; speedup vs baseline: 1.0954x; 1.0768x over previous
//
#include <hip/hip_runtime.h>
#include <cstdint>

// Block_32401233281211: SAM-style windowed-attention transformer block.
// I/O dtype: FLOAT32. Internal GEMMs + attention: bf16 MFMA.
// B=8, H=W=64, C=768, heads=12, hd=64, FF=3072, WS=14 -> pad to 70x70,
// 200 windows x 196 tokens = 39200 window-token rows.
// History: R8 (gemm_bt 128^2 2-barrier + attention half-blocks) = 1445.8us,
//   best total. R9-R13 pipelined GEMM redesigns (256^2, counted vmcnt,
//   tri-buffer fine interleave) all pinned MfmaUtil 18-20% and were net
//   neutral-to-worse. Per pre-commitment: stop re-deriving GEMM structure.
// R14 (this round): REVERT to R8 wholesale; single variable changed:
//   gemm_bt LDS swizzle. R8's BK=32 64B-row fragment reads were an 8-way
//   bank conflict (SQ_LDS_BANK_CONFLICT 1.9e7, ~2.9x LDS-read cost m136).
//   Fix = R12/R13's HW-verified involution: chunk' = chunk ^ ((row>>1)&3),
//   applied on the GLOBAL staging source (LDS dest stays linear, required
//   by global_load_lds) and on the fragment-read offset. Even-row classes
//   repeat each chunk exactly 2x -> 2-way aliasing = free.
//   Staging col: ((lane&3) ^ ((lane>>3)&3))*8   (16t term drops mod 4)
//   Read offset: ((quad ^ ((l16>>1)&3)) << 3)   (wr*64, i*16 drop mod 4)

typedef unsigned short u16;
typedef __attribute__((ext_vector_type(8))) short short8;   // 8 x bf16
typedef __attribute__((ext_vector_type(4))) float f32x4;

__device__ __forceinline__ u16 f2b(float f) {
    union { float f; unsigned int i; } x; x.f = f;
    unsigned int u = x.i;
    return (u16)((u + 0x7fffu + ((u >> 16) & 1u)) >> 16);   // RNE
}
__device__ __forceinline__ float b2f(u16 u) {
    union { unsigned int i; float f; } x; x.i = ((unsigned int)u) << 16; return x.f;
}

// async global->LDS, 16 B per lane. LDS dest = wave-uniform base + lane*16.
__device__ __forceinline__ void gload16(const u16* g, u16* l) {
    __builtin_amdgcn_global_load_lds(
        (const __attribute__((address_space(1))) unsigned int*)g,
        (__attribute__((address_space(3))) unsigned int*)l, 16, 0, 0);
}

// bijective XCD swizzle (m204)
__device__ __forceinline__ int xcd_swz(int bid, int nwg) {
    int q = nwg >> 3, r = nwg & 7;
    int x = bid & 7, lo = bid >> 3;
    return (x < r ? x * (q + 1) : r * (q + 1) + (x - r) * q) + lo;
}

// ---------------------------------------------------------------- transpose
__global__ __launch_bounds__(256) void transpose_k(
    const float* __restrict__ in, u16* __restrict__ out, int R, int C)
{
    __shared__ float tile[32][33];
    int bpc = C >> 5;
    int r0 = (blockIdx.x / bpc) << 5;
    int c0 = (blockIdx.x % bpc) << 5;
    int lx = threadIdx.x & 31, ly = threadIdx.x >> 5;
#pragma unroll
    for (int s = 0; s < 32; s += 8)
        tile[ly + s][lx] = in[(size_t)(r0 + ly + s) * C + c0 + lx];
    __syncthreads();
#pragma unroll
    for (int s = 0; s < 32; s += 8)
        out[(size_t)(c0 + ly + s) * R + r0 + lx] = f2b(tile[lx][ly + s]);
}

// ---------------------------------------------------------------- layernorm
__global__ __launch_bounds__(256) void ln_kernel(
    const float* __restrict__ in, const float* __restrict__ g,
    const float* __restrict__ beta, u16* __restrict__ out, int windowed,
    int row_base)
{
    __shared__ float sbuf[4];
    int tid = threadIdx.x;
    size_t orow = (size_t)blockIdx.x * 768;
    size_t irow;
    if (windowed) {
        int r = row_base + blockIdx.x;
        int win = r / 196, t = r % 196;
        int p = t / 14, q = t % 14;
        int b = win / 25, wt = win % 25;
        int i = (wt / 5) * 14 + p, j = (wt % 5) * 14 + q;
        if (i >= 64 || j >= 64) {
            out[orow + tid] = 0; out[orow + tid + 256] = 0; out[orow + tid + 512] = 0;
            return;
        }
        irow = (((size_t)b * 64 + i) * 64 + j) * 768;
    } else {
        irow = (size_t)blockIdx.x * 768;
    }
    float v0 = in[irow + tid];
    float v1 = in[irow + tid + 256];
    float v2 = in[irow + tid + 512];
    float s = v0 + v1 + v2;
#pragma unroll
    for (int off = 32; off; off >>= 1) s += __shfl_xor(s, off, 64);
    if ((tid & 63) == 0) sbuf[tid >> 6] = s;
    __syncthreads();
    float mean = (sbuf[0] + sbuf[1] + sbuf[2] + sbuf[3]) * (1.f / 768.f);
    __syncthreads();
    float d0 = v0 - mean, d1 = v1 - mean, d2 = v2 - mean;
    float sq = d0 * d0 + d1 * d1 + d2 * d2;
#pragma unroll
    for (int off = 32; off; off >>= 1) sq += __shfl_xor(sq, off, 64);
    if ((tid & 63) == 0) sbuf[tid >> 6] = sq;
    __syncthreads();
    float var = (sbuf[0] + sbuf[1] + sbuf[2] + sbuf[3]) * (1.f / 768.f);
    float rs = rsqrtf(var + 1e-6f);
    out[orow + tid]       = f2b(d0 * rs * g[tid]       + beta[tid]);
    out[orow + tid + 256] = f2b(d1 * rs * g[tid + 256] + beta[tid + 256]);
    out[orow + tid + 512] = f2b(d2 * rs * g[tid + 512] + beta[tid + 512]);
}

// ---------------------------------------------------------------- GEMM
// C(MxN) = A(MxK) @ Bt(NxK)^T + bias, bf16 in / f32 acc, MFMA 16x16x32.
// 128x128 tile, BK=32 (R8 structure, best measured). Staging via
// global_load_lds width=16: instr t=2*wave+j covers tile rows [16t,16t+16):
// lane i -> global row m0+16t+(i>>2), chunk ((i&3)^((i>>3)&3)) of 4x16B
// == LDS base(t*512 elems) + lane*16 B (linear dest).
// Swizzle (R14): LDS chunk c of row r holds global chunk c ^ ((r>>1)&3);
// fragment read offset = (quad ^ ((l16>>1)&3))*8 elems. 2-way = free.
// Tail rows >= M stage garbage; consumed only by epilogue rows >= M (skipped).
#define BM 128
#define BN 128
#define BK 32

template <int EPI>
__global__ __launch_bounds__(256) void gemm_bt(
    const u16* __restrict__ A, const u16* __restrict__ Bt,
    const float* __restrict__ bias, void* __restrict__ CoutV,
    const float* __restrict__ resid, int M, int N, int K, int row_base)
{
    __shared__ __align__(16) u16 As[BM * BK];
    __shared__ __align__(16) u16 Bs[BN * BK];
    const int tid = threadIdx.x;
    const int lane = tid & 63, wave = tid >> 6;
    const int wr = wave >> 1, wc = wave & 1;
    const int quad = lane >> 4, l16 = lane & 15;
    const int ntile = N / BN;
    const int swz = xcd_swz(blockIdx.x, gridDim.x);
    const int m0 = (swz / ntile) * BM;
    const int n0 = (swz % ntile) * BN;

    f32x4 acc[4][4] = {};

    // per-lane source offsets for the two staging instructions of this wave.
    // R14: global k-offset carries the inverse swizzle (involution):
    //   row = 16t + (lane>>2); f(row) = (row>>1)&3 = (lane>>3)&3  (16t = 0 mod 4)
    const int t0 = wave * 2;
    const int kswz = (((lane & 3) ^ ((lane >> 3) & 3)) * 8);
    const size_t arow0 = (size_t)(m0 + t0 * 16 + (lane >> 2)) * K + kswz;
    const size_t arow1 = arow0 + (size_t)16 * K;
    const size_t brow0 = (size_t)(n0 + t0 * 16 + (lane >> 2)) * K + kswz;
    const size_t brow1 = brow0 + (size_t)16 * K;
    u16* lA0 = As + t0 * 16 * BK;
    u16* lA1 = As + (t0 + 1) * 16 * BK;
    u16* lB0 = Bs + t0 * 16 * BK;
    u16* lB1 = Bs + (t0 + 1) * 16 * BK;

    // fragment-read chunk: quad ^ ((row>>1)&3); row = wr*64+i*16+l16 ->
    // (row>>1)&3 = (l16>>1)&3 (wr*64, i*16 drop mod 4)
    const int rchunk = ((quad ^ ((l16 >> 1) & 3)) << 3);

    for (int k0 = 0; k0 < K; k0 += BK) {
        __syncthreads();                     // previous tile fully consumed
        gload16(A + arow0 + k0, lA0);
        gload16(A + arow1 + k0, lA1);
        gload16(Bt + brow0 + k0, lB0);
        gload16(Bt + brow1 + k0, lB1);
        __syncthreads();                     // drain vmcnt (compiler-inserted)
        short8 af[4], bfr[4];
#pragma unroll
        for (int i = 0; i < 4; i++)
            af[i] = *(const short8*)(As + (wr * 64 + i * 16 + l16) * BK + rchunk);
#pragma unroll
        for (int i = 0; i < 4; i++)
            bfr[i] = *(const short8*)(Bs + (wc * 64 + i * 16 + l16) * BK + rchunk);
        __builtin_amdgcn_s_setprio(1);
#pragma unroll
        for (int mi = 0; mi < 4; mi++)
#pragma unroll
            for (int ni = 0; ni < 4; ni++)
                acc[mi][ni] = __builtin_amdgcn_mfma_f32_16x16x32_bf16(
                    af[mi], bfr[ni], acc[mi][ni], 0, 0, 0);
        __builtin_amdgcn_s_setprio(0);
    }

#pragma unroll
    for (int mi = 0; mi < 4; mi++) {
#pragma unroll
        for (int ni = 0; ni < 4; ni++) {
            const int gn = n0 + wc * 64 + ni * 16 + l16;
            const float bv = bias[gn];
#pragma unroll
            for (int r = 0; r < 4; r++) {
                const int row = m0 + wr * 64 + mi * 16 + quad * 4 + r;
                if (row >= M) continue;
                float v = acc[mi][ni][r] + bv;
                if (EPI == 0) {
                    ((u16*)CoutV)[(size_t)row * N + gn] = f2b(v);
                } else if (EPI == 1) {
                    int grow = row_base + row;
                    int win = grow / 196, t = grow % 196;
                    int p = t / 14, q = t % 14;
                    int b = win / 25, wt = win % 25;
                    int i = (wt / 5) * 14 + p, j = (wt % 5) * 14 + q;
                    if (i < 64 && j < 64) {
                        size_t idx = (((size_t)b * 64 + i) * 64 + j) * 768 + gn;
                        ((float*)CoutV)[idx] = resid[idx] + v;
                    }
                } else if (EPI == 2) {
                    float gl = 0.5f * v * (1.0f + erff(v * 0.70710678118654752f));
                    ((u16*)CoutV)[(size_t)row * N + gn] = f2b(gl);
                } else {
                    size_t idx = (size_t)(row_base + row) * 768 + gn;
                    ((float*)CoutV)[idx] = resid[idx] + v;
                }
            }
        }
    }
}

// ---------------------------------------------------------------- attention v5
// (unchanged from R8 — verified passing)
#define AT_W 72
#define PB_W 40

__global__ __launch_bounds__(256) void attn_mfma(
    const u16* __restrict__ qkv,          // [nw*196][2304] = [..][3][12][64]
    const float* __restrict__ relh, const float* __restrict__ relw, // [27][64]
    u16* __restrict__ out)                // [nw*196][768]
{
    __shared__ __align__(16) u16 pbuf[4][32 * PB_W];     // 10240 B (rel_ext alias)
    __shared__ __align__(16) u16 Kc[64 * AT_W];          //  9216 B
    __shared__ __align__(16) u16 Vt[64 * AT_W];          //  9216 B
    u16* rel_ext = &pbuf[0][0];                          // 128*32*2 = 8192 B

    const int nwg = gridDim.x;
    const int swzb = xcd_swz(blockIdx.x, nwg);
    const int win = swzb / 24, rem = swzb % 24;
    const int head = rem >> 1, half = rem & 1;
    const int row0 = half * 128;
    const int tid = threadIdx.x, lane = tid & 63, wave = tid >> 6;
    const int quad = lane >> 4, l16 = lane & 15;
    const size_t base = (size_t)win * 196 * 2304 + (size_t)head * 64;

    short8 qf[2][2];
#pragma unroll
    for (int mi = 0; mi < 2; mi++) {
        int tok = row0 + wave * 32 + mi * 16 + l16;
        int rt = tok < 196 ? tok : 195;
        const u16* qp = qkv + base + (size_t)rt * 2304 + quad * 8;
        qf[mi][0] = *(const short8*)(qp);
        qf[mi][1] = *(const short8*)(qp + 32);
    }

    for (int e = tid; e < 64 * 64; e += 256) {
        int rr = e >> 6, cc = e & 63;
        float v = 0.f;
        if (rr < 27)      v = 8.f * relh[rr * 64 + cc];
        else if (rr < 54) v = 8.f * relw[(rr - 27) * 64 + cc];
        Kc[rr * AT_W + cc] = f2b(v);
    }
    if (tid < 128) {
        u16* rp = rel_ext + tid * 32;
        uint4 z = make_uint4(0u, 0u, 0u, 0u);
        *(uint4*)(rp) = z; *(uint4*)(rp + 8) = z;
        *(uint4*)(rp + 16) = z; *(uint4*)(rp + 24) = z;
        rp[31] = f2b(-1e30f);
    }
    __syncthreads();

#pragma unroll
    for (int cb = 0; cb < 2; cb++) {
#pragma unroll
        for (int nt = 0; nt < 2; nt++) {
            const u16* kp_ = Kc + (cb * 32 + nt * 16 + l16) * AT_W + quad * 8;
            short8 b0 = *(const short8*)(kp_);
            short8 b1 = *(const short8*)(kp_ + 32);
            int i = cb * 32 + nt * 16 + l16;
#pragma unroll
            for (int mi = 0; mi < 2; mi++) {
                f32x4 c = {};
                c = __builtin_amdgcn_mfma_f32_16x16x32_bf16(qf[mi][0], b0, c, 0, 0, 0);
                c = __builtin_amdgcn_mfma_f32_16x16x32_bf16(qf[mi][1], b1, c, 0, 0, 0);
#pragma unroll
                for (int r = 0; r < 4; r++) {
                    int row = wave * 32 + mi * 16 + quad * 4 + r;
                    int grow = row0 + row;
                    int rowB = grow < 196 ? grow : 195;
                    int p = rowB / 14, qq = rowB % 14;
                    if (i < 27) {
                        int t = p + 13 - i;
                        if (t >= 0 && t < 14) rel_ext[row * 32 + t] = f2b(c[r]);
                    } else if (i < 54) {
                        int t = qq + 13 - (i - 27);
                        if (t >= 0 && t < 14) rel_ext[row * 32 + 14 + t] = f2b(c[r]);
                    }
                }
            }
        }
    }
    short8 qe[2];
#pragma unroll
    for (int mi = 0; mi < 2; mi++)
        qe[mi] = *(const short8*)(rel_ext + (wave * 32 + mi * 16 + l16) * 32 + quad * 8);

    f32x4 acc[2][4] = {};
    float ml_[2][4], ll_[2][4];
#pragma unroll
    for (int mi = 0; mi < 2; mi++)
#pragma unroll
        for (int r = 0; r < 4; r++) { ml_[mi][r] = -1e30f; ll_[mi][r] = 0.f; }

#pragma unroll 1
    for (int c = 0; c < 4; c++) {
        const int kbase = c * 64;
        __syncthreads();
        {
            int key = tid >> 2;
            int cg  = (tid & 3) << 4;
            int gk = kbase + key;
            uint4 k0 = make_uint4(0u,0u,0u,0u), k1 = k0, v0 = k0, v1 = k0;
            if (gk < 196) {
                const u16* kp_ = qkv + base + 768  + (size_t)gk * 2304 + cg;
                const u16* vp_ = qkv + base + 1536 + (size_t)gk * 2304 + cg;
                k0 = *(const uint4*)(kp_); k1 = *(const uint4*)(kp_ + 8);
                v0 = *(const uint4*)(vp_); v1 = *(const uint4*)(vp_ + 8);
            }
            *(uint4*)(Kc + key * AT_W + cg)     = k0;
            *(uint4*)(Kc + key * AT_W + cg + 8) = k1;
            union { uint4 u; u16 h[8]; } a, b; a.u = v0; b.u = v1;
#pragma unroll
            for (int i = 0; i < 8; i++) Vt[(cg + i) * AT_W + key] = a.h[i];
#pragma unroll
            for (int i = 0; i < 8; i++) Vt[(cg + 8 + i) * AT_W + key] = b.h[i];
        }
        __syncthreads();

        short8 bo[4];
        {
            const u16 one = 0x3F80;
#pragma unroll
            for (int nt = 0; nt < 4; nt++) {
                int key = kbase + nt * 16 + l16;
                int inval = key >= 196;
                int kp = key / 14, kq = key - kp * 14;
                union { short8 s; u16 h[8]; } u;
#pragma unroll
                for (int j = 0; j < 8; j++) {
                    int t = quad * 8 + j;
                    u16 v = 0;
                    if (!inval && t == kp) v = one;
                    if (!inval && t >= 14 && (t - 14) == kq) v = one;
                    if (inval && t == 31) v = one;
                    u.h[j] = v;
                }
                bo[nt] = u.s;
            }
        }

        f32x4 s23[2][2];
#pragma unroll
        for (int mi = 0; mi < 2; mi++) {
            f32x4 s[4];
            __builtin_amdgcn_s_setprio(1);
#pragma unroll
            for (int nt = 0; nt < 4; nt++) {
                const u16* kp_ = Kc + (nt * 16 + l16) * AT_W + quad * 8;
                short8 kf0 = *(const short8*)(kp_);
                short8 kf1 = *(const short8*)(kp_ + 32);
                f32x4 t = {};
                t = __builtin_amdgcn_mfma_f32_16x16x32_bf16(qf[mi][0], kf0, t, 0, 0, 0);
                t = __builtin_amdgcn_mfma_f32_16x16x32_bf16(qf[mi][1], kf1, t, 0, 0, 0);
                t = __builtin_amdgcn_mfma_f32_16x16x32_bf16(qe[mi],    bo[nt], t, 0, 0, 0);
                s[nt] = t * 0.125f;
            }
            __builtin_amdgcn_s_setprio(0);
#pragma unroll
            for (int r = 0; r < 4; r++) {
                float mx = fmaxf(fmaxf(s[0][r], s[1][r]), fmaxf(s[2][r], s[3][r]));
#pragma unroll
                for (int off = 8; off; off >>= 1) mx = fmaxf(mx, __shfl_xor(mx, off, 16));
                float mo = ml_[mi][r];
                float mn = fmaxf(mo, mx);
                float alpha = __expf(mo - mn);
                ml_[mi][r] = mn;
                float p0 = __expf(s[0][r] - mn), p1 = __expf(s[1][r] - mn);
                float p2 = __expf(s[2][r] - mn), p3 = __expf(s[3][r] - mn);
                float ps = (p0 + p1) + (p2 + p3);
#pragma unroll
                for (int off = 8; off; off >>= 1) ps += __shfl_xor(ps, off, 16);
                ll_[mi][r] = ll_[mi][r] * alpha + ps;
#pragma unroll
                for (int ni = 0; ni < 4; ni++) acc[mi][ni][r] *= alpha;
                s[0][r] = p0; s[1][r] = p1; s[2][r] = p2; s[3][r] = p3;
            }
#pragma unroll
            for (int nt = 0; nt < 2; nt++)
#pragma unroll
                for (int r = 0; r < 4; r++)
                    pbuf[wave][(mi * 16 + quad * 4 + r) * PB_W + nt * 16 + l16] = f2b(s[nt][r]);
            s23[mi][0] = s[2]; s23[mi][1] = s[3];
        }

        __builtin_amdgcn_s_setprio(1);
#pragma unroll
        for (int mi = 0; mi < 2; mi++) {
            short8 pf = *(const short8*)(pbuf[wave] + (mi * 16 + l16) * PB_W + quad * 8);
#pragma unroll
            for (int ni = 0; ni < 4; ni++) {
                short8 vfn = *(const short8*)(Vt + (ni * 16 + l16) * AT_W + quad * 8);
                acc[mi][ni] = __builtin_amdgcn_mfma_f32_16x16x32_bf16(pf, vfn, acc[mi][ni], 0, 0, 0);
            }
        }
        __builtin_amdgcn_s_setprio(0);
#pragma unroll
        for (int mi = 0; mi < 2; mi++)
#pragma unroll
            for (int h = 0; h < 2; h++)
#pragma unroll
                for (int r = 0; r < 4; r++)
                    pbuf[wave][(mi * 16 + quad * 4 + r) * PB_W + h * 16 + l16] = f2b(s23[mi][h][r]);
        __builtin_amdgcn_s_setprio(1);
#pragma unroll
        for (int mi = 0; mi < 2; mi++) {
            short8 pf = *(const short8*)(pbuf[wave] + (mi * 16 + l16) * PB_W + quad * 8);
#pragma unroll
            for (int ni = 0; ni < 4; ni++) {
                short8 vfn = *(const short8*)(Vt + (ni * 16 + l16) * AT_W + 32 + quad * 8);
                acc[mi][ni] = __builtin_amdgcn_mfma_f32_16x16x32_bf16(pf, vfn, acc[mi][ni], 0, 0, 0);
            }
        }
        __builtin_amdgcn_s_setprio(0);
    }

#pragma unroll
    for (int mi = 0; mi < 2; mi++)
#pragma unroll
        for (int r = 0; r < 4; r++) {
            int tok = row0 + wave * 32 + mi * 16 + quad * 4 + r;
            if (tok < 196) {
                float inv = 1.f / ll_[mi][r];
                size_t ob = (size_t)(win * 196 + tok) * 768 + head * 64;
#pragma unroll
                for (int ni = 0; ni < 4; ni++)
                    out[ob + ni * 16 + l16] = f2b(acc[mi][ni][r] * inv);
            }
        }
}

// ---------------------------------------------------------------- launch
extern "C" void kernel_launch(void* const* d_in, const int* in_sizes, int n_in,
                              void* d_out, int out_size, void* d_ws, size_t ws_size,
                              hipStream_t stream)
{
    const float* x      = (const float*)d_in[0];
    const float* g1     = (const float*)d_in[1];
    const float* beta1  = (const float*)d_in[2];
    const float* w_qkv  = (const float*)d_in[3];
    const float* b_qkv  = (const float*)d_in[4];
    const float* w_proj = (const float*)d_in[5];
    const float* b_proj = (const float*)d_in[6];
    const float* rph    = (const float*)d_in[7];
    const float* rpw    = (const float*)d_in[8];
    const float* g2     = (const float*)d_in[9];
    const float* beta2  = (const float*)d_in[10];
    const float* w_fc1  = (const float*)d_in[11];
    const float* b_fc1  = (const float*)d_in[12];
    const float* w_fc2  = (const float*)d_in[13];
    const float* b_fc2  = (const float*)d_in[14];
    float* out = (float*)d_out;

    const size_t WT = 14155776;
    size_t b1 = 0, b2 = 0;
    int nc = 0, mc = 0;
    auto fits = [&](int a, int m) -> bool {
        size_t rows = (size_t)(200 / a) * 196, toks = (size_t)32768 / m;
        size_t bb1 = rows * 768 * 2 >= toks * 768 * 2 ? rows * 768 * 2 : toks * 768 * 2;
        size_t bb2 = rows * 2304 * 2 >= toks * 3072 * 2 ? rows * 2304 * 2 : toks * 3072 * 2;
        if (WT + bb1 + bb2 <= ws_size) { b1 = bb1; b2 = bb2; nc = a; mc = m; return true; }
        return false;
    };
    if (!fits(1, 1) && !fits(1, 2) && !fits(2, 2) && !fits(2, 4) && !fits(4, 4))
        return;   // diagnostic: leaves d_out untouched

    char* ws = (char*)d_ws;
    u16* wt0 = (u16*)ws;                               // qkv^T  2304x768
    u16* wt1 = wt0 + 2304 * 768;                       // proj^T  768x768
    u16* wt2 = wt1 + 768 * 768;                        // fc1^T  3072x768
    u16* wt3 = wt2 + 3072 * 768;                       // fc2^T   768x3072
    u16* buf1 = (u16*)(ws + WT);
    u16* buf2 = (u16*)(ws + WT + b1);

    dim3 blk(256);

    transpose_k<<<(768/32)*(2304/32), blk, 0, stream>>>(w_qkv,  wt0, 768, 2304);
    transpose_k<<<(768/32)*(768/32),  blk, 0, stream>>>(w_proj, wt1, 768, 768);
    transpose_k<<<(768/32)*(3072/32), blk, 0, stream>>>(w_fc1,  wt2, 768, 3072);
    transpose_k<<<(3072/32)*(768/32), blk, 0, stream>>>(w_fc2,  wt3, 3072, 768);

    // ---- attention phase: nc chunks of (200/nc) windows ----
    {
        const int nw = 200 / nc, rows = nw * 196;
        const int mt = (rows + 127) / 128;
        for (int c = 0; c < nc; c++) {
            const int rb = c * rows;
            ln_kernel<<<rows, blk, 0, stream>>>(x, g1, beta1, buf1, 1, rb);
            gemm_bt<0><<<dim3(mt * (2304/128)), blk, 0, stream>>>(
                buf1, wt0, b_qkv, buf2, nullptr, rows, 2304, 768, 0);
            attn_mfma<<<nw * 24, blk, 0, stream>>>(buf2, rph, rpw, buf1);
            gemm_bt<1><<<dim3(mt * (768/128)), blk, 0, stream>>>(
                buf1, wt1, b_proj, out, x, rows, 768, 768, rb);
        }
    }

    // ---- MLP phase: mc chunks of (32768/mc) tokens ----
    {
        const int tk = 32768 / mc;
        const int mt2 = tk / 128;
        for (int c = 0; c < mc; c++) {
            const int rb = c * tk;
            ln_kernel<<<tk, blk, 0, stream>>>(
                out + (size_t)rb * 768, g2, beta2, buf1, 0, 0);
            gemm_bt<2><<<dim3(mt2 * (3072/128)), blk, 0, stream>>>(
                buf1, wt2, b_fc1, buf2, nullptr, tk, 3072, 768, 0);
            gemm_bt<3><<<dim3(mt2 * (768/128)), blk, 0, stream>>>(
                buf2, wt3, b_fc2, out, out, tk, 768, 3072, rb);
        }
    }
}

// Round 9
// 1340.919 us; speedup vs baseline: 1.1631x; 1.0618x over previous
//
#include <hip/hip_runtime.h>
#include <cstdint>

// Block_32401233281211: SAM-style windowed-attention transformer block.
// I/O dtype: FLOAT32. Internal GEMMs + attention: bf16 MFMA.
// B=8, H=W=64, C=768, heads=12, hd=64, FF=3072, WS=14 -> pad to 70x70,
// 200 windows x 196 tokens = 39200 window-token rows.
// History: R8 1445.8us (gemm_bt 128^2 BK=32 + attn half-blocks). R9-R13
//   pipelined redesigns all null (MfmaUtil 18-20%). R14 1423.8us: swizzle
//   killed 1.9e7 bank conflicts -> only ~5us/dispatch (conflicts were
//   TLP-hidden; LDS reads not on critical path).
// R15 (this round): single variable vs R14 -> BK 32->64 in the SAME
//   2-barrier structure. Rationale: per-K-tile cost ~5600cyc, MFMA only
//   ~1240; fixed stage/drain/barrier overhead dominates and K=768 pays it
//   24x. BK=64 halves barrier-pairs (24->12, fc2 48->24), doubles MFMA per
//   drain (16->32). Staging/read pattern lifted verbatim from R10's gemm128
//   (HW-verified: passed, 0 bank conflicts). Frags read per-ks half so the
//   live register set matches R14 (~3 blocks/CU unchanged; LDS 32KB).

typedef unsigned short u16;
typedef __attribute__((ext_vector_type(8))) short short8;   // 8 x bf16
typedef __attribute__((ext_vector_type(4))) float f32x4;

__device__ __forceinline__ u16 f2b(float f) {
    union { float f; unsigned int i; } x; x.f = f;
    unsigned int u = x.i;
    return (u16)((u + 0x7fffu + ((u >> 16) & 1u)) >> 16);   // RNE
}
__device__ __forceinline__ float b2f(u16 u) {
    union { unsigned int i; float f; } x; x.i = ((unsigned int)u) << 16; return x.f;
}

// async global->LDS, 16 B per lane. LDS dest = wave-uniform base + lane*16.
__device__ __forceinline__ void gload16(const u16* g, u16* l) {
    __builtin_amdgcn_global_load_lds(
        (const __attribute__((address_space(1))) unsigned int*)g,
        (__attribute__((address_space(3))) unsigned int*)l, 16, 0, 0);
}

// bijective XCD swizzle (m204)
__device__ __forceinline__ int xcd_swz(int bid, int nwg) {
    int q = nwg >> 3, r = nwg & 7;
    int x = bid & 7, lo = bid >> 3;
    return (x < r ? x * (q + 1) : r * (q + 1) + (x - r) * q) + lo;
}

// ---------------------------------------------------------------- transpose
__global__ __launch_bounds__(256) void transpose_k(
    const float* __restrict__ in, u16* __restrict__ out, int R, int C)
{
    __shared__ float tile[32][33];
    int bpc = C >> 5;
    int r0 = (blockIdx.x / bpc) << 5;
    int c0 = (blockIdx.x % bpc) << 5;
    int lx = threadIdx.x & 31, ly = threadIdx.x >> 5;
#pragma unroll
    for (int s = 0; s < 32; s += 8)
        tile[ly + s][lx] = in[(size_t)(r0 + ly + s) * C + c0 + lx];
    __syncthreads();
#pragma unroll
    for (int s = 0; s < 32; s += 8)
        out[(size_t)(c0 + ly + s) * R + r0 + lx] = f2b(tile[lx][ly + s]);
}

// ---------------------------------------------------------------- layernorm
__global__ __launch_bounds__(256) void ln_kernel(
    const float* __restrict__ in, const float* __restrict__ g,
    const float* __restrict__ beta, u16* __restrict__ out, int windowed,
    int row_base)
{
    __shared__ float sbuf[4];
    int tid = threadIdx.x;
    size_t orow = (size_t)blockIdx.x * 768;
    size_t irow;
    if (windowed) {
        int r = row_base + blockIdx.x;
        int win = r / 196, t = r % 196;
        int p = t / 14, q = t % 14;
        int b = win / 25, wt = win % 25;
        int i = (wt / 5) * 14 + p, j = (wt % 5) * 14 + q;
        if (i >= 64 || j >= 64) {
            out[orow + tid] = 0; out[orow + tid + 256] = 0; out[orow + tid + 512] = 0;
            return;
        }
        irow = (((size_t)b * 64 + i) * 64 + j) * 768;
    } else {
        irow = (size_t)blockIdx.x * 768;
    }
    float v0 = in[irow + tid];
    float v1 = in[irow + tid + 256];
    float v2 = in[irow + tid + 512];
    float s = v0 + v1 + v2;
#pragma unroll
    for (int off = 32; off; off >>= 1) s += __shfl_xor(s, off, 64);
    if ((tid & 63) == 0) sbuf[tid >> 6] = s;
    __syncthreads();
    float mean = (sbuf[0] + sbuf[1] + sbuf[2] + sbuf[3]) * (1.f / 768.f);
    __syncthreads();
    float d0 = v0 - mean, d1 = v1 - mean, d2 = v2 - mean;
    float sq = d0 * d0 + d1 * d1 + d2 * d2;
#pragma unroll
    for (int off = 32; off; off >>= 1) sq += __shfl_xor(sq, off, 64);
    if ((tid & 63) == 0) sbuf[tid >> 6] = sq;
    __syncthreads();
    float var = (sbuf[0] + sbuf[1] + sbuf[2] + sbuf[3]) * (1.f / 768.f);
    float rs = rsqrtf(var + 1e-6f);
    out[orow + tid]       = f2b(d0 * rs * g[tid]       + beta[tid]);
    out[orow + tid + 256] = f2b(d1 * rs * g[tid + 256] + beta[tid + 256]);
    out[orow + tid + 512] = f2b(d2 * rs * g[tid + 512] + beta[tid + 512]);
}

// ---------------------------------------------------------------- GEMM
// C(MxN) = A(MxK) @ Bt(NxK)^T + bias, bf16 in / f32 acc, MFMA 16x16x32.
// 128x128 tile, BK=64, 4 waves, 2-barrier loop (R8 structure, BK doubled).
// Staging (R10-verified): per wave 4 A + 4 B gload16; segment = 8 rows x
// 128 B; lane i -> row (i>>3), src k-chunk (i&7)^(i>>3) (inverse swizzle),
// LDS dest linear. Read: frag(row,ks) at row*64 + (((ks*4+quad)^(row&7))*8;
// row&7 == l16&7. 0 bank conflicts (measured R10/R11).
// Tail rows >= M stage garbage; consumed only by epilogue rows >= M (skipped).
#define BM 128
#define BN 128
#define BK 64

template <int EPI>
__global__ __launch_bounds__(256) void gemm_bt(
    const u16* __restrict__ A, const u16* __restrict__ Bt,
    const float* __restrict__ bias, void* __restrict__ CoutV,
    const float* __restrict__ resid, int M, int N, int K, int row_base)
{
    __shared__ __align__(16) u16 As[BM * BK];   // 16 KB
    __shared__ __align__(16) u16 Bs[BN * BK];   // 16 KB
    const int tid = threadIdx.x;
    const int lane = tid & 63, wave = tid >> 6;
    const int wr = wave >> 1, wc = wave & 1;
    const int quad = lane >> 4, l16 = lane & 15;
    const int l7 = lane & 7;
    const int ntile = N / BN;
    const int swz = xcd_swz(blockIdx.x, gridDim.x);
    const int m0 = (swz / ntile) * BM;
    const int n0 = (swz % ntile) * BN;

    f32x4 acc[4][4] = {};

    // staging lane constants (R10-verified swizzle involution)
    const int rl = lane >> 3;                      // segment row 0..7
    const int cl = ((lane & 7) ^ rl) << 3;         // source k-elem offset
    size_t aoff[4], boff[4];
#pragma unroll
    for (int q = 0; q < 4; q++) {
        aoff[q] = (size_t)(m0 + wave * 32 + q * 8 + rl) * K + cl;
        boff[q] = (size_t)(n0 + wave * 32 + q * 8 + rl) * K + cl;
    }
    const int lws = wave * 2048;                   // wave's staging base (elems)

    for (int k0 = 0; k0 < K; k0 += BK) {
        __syncthreads();                     // previous tile fully consumed
#pragma unroll
        for (int q = 0; q < 4; q++) {
            gload16(A  + aoff[q] + k0, As + lws + q * 512);
            gload16(Bt + boff[q] + k0, Bs + lws + q * 512);
        }
        __syncthreads();                     // drain vmcnt (compiler-inserted)
#pragma unroll
        for (int ks = 0; ks < 2; ks++) {
            short8 af[4], bfr[4];
            const int rsw = (((ks << 2) + quad) ^ l7) << 3;
#pragma unroll
            for (int i = 0; i < 4; i++)
                af[i] = *(const short8*)(As + (wr * 64 + i * 16 + l16) * 64 + rsw);
#pragma unroll
            for (int i = 0; i < 4; i++)
                bfr[i] = *(const short8*)(Bs + (wc * 64 + i * 16 + l16) * 64 + rsw);
            __builtin_amdgcn_s_setprio(1);
#pragma unroll
            for (int mi = 0; mi < 4; mi++)
#pragma unroll
                for (int ni = 0; ni < 4; ni++)
                    acc[mi][ni] = __builtin_amdgcn_mfma_f32_16x16x32_bf16(
                        af[mi], bfr[ni], acc[mi][ni], 0, 0, 0);
            __builtin_amdgcn_s_setprio(0);
        }
    }

#pragma unroll
    for (int mi = 0; mi < 4; mi++) {
#pragma unroll
        for (int ni = 0; ni < 4; ni++) {
            const int gn = n0 + wc * 64 + ni * 16 + l16;
            const float bv = bias[gn];
#pragma unroll
            for (int r = 0; r < 4; r++) {
                const int row = m0 + wr * 64 + mi * 16 + quad * 4 + r;
                if (row >= M) continue;
                float v = acc[mi][ni][r] + bv;
                if (EPI == 0) {
                    ((u16*)CoutV)[(size_t)row * N + gn] = f2b(v);
                } else if (EPI == 1) {
                    int grow = row_base + row;
                    int win = grow / 196, t = grow % 196;
                    int p = t / 14, q = t % 14;
                    int b = win / 25, wt = win % 25;
                    int i = (wt / 5) * 14 + p, j = (wt % 5) * 14 + q;
                    if (i < 64 && j < 64) {
                        size_t idx = (((size_t)b * 64 + i) * 64 + j) * 768 + gn;
                        ((float*)CoutV)[idx] = resid[idx] + v;
                    }
                } else if (EPI == 2) {
                    float gl = 0.5f * v * (1.0f + erff(v * 0.70710678118654752f));
                    ((u16*)CoutV)[(size_t)row * N + gn] = f2b(gl);
                } else {
                    size_t idx = (size_t)(row_base + row) * 768 + gn;
                    ((float*)CoutV)[idx] = resid[idx] + v;
                }
            }
        }
    }
}

// ---------------------------------------------------------------- attention v5
// (unchanged from R8 — verified passing)
#define AT_W 72
#define PB_W 40

__global__ __launch_bounds__(256) void attn_mfma(
    const u16* __restrict__ qkv,          // [nw*196][2304] = [..][3][12][64]
    const float* __restrict__ relh, const float* __restrict__ relw, // [27][64]
    u16* __restrict__ out)                // [nw*196][768]
{
    __shared__ __align__(16) u16 pbuf[4][32 * PB_W];     // 10240 B (rel_ext alias)
    __shared__ __align__(16) u16 Kc[64 * AT_W];          //  9216 B
    __shared__ __align__(16) u16 Vt[64 * AT_W];          //  9216 B
    u16* rel_ext = &pbuf[0][0];                          // 128*32*2 = 8192 B

    const int nwg = gridDim.x;
    const int swzb = xcd_swz(blockIdx.x, nwg);
    const int win = swzb / 24, rem = swzb % 24;
    const int head = rem >> 1, half = rem & 1;
    const int row0 = half * 128;
    const int tid = threadIdx.x, lane = tid & 63, wave = tid >> 6;
    const int quad = lane >> 4, l16 = lane & 15;
    const size_t base = (size_t)win * 196 * 2304 + (size_t)head * 64;

    short8 qf[2][2];
#pragma unroll
    for (int mi = 0; mi < 2; mi++) {
        int tok = row0 + wave * 32 + mi * 16 + l16;
        int rt = tok < 196 ? tok : 195;
        const u16* qp = qkv + base + (size_t)rt * 2304 + quad * 8;
        qf[mi][0] = *(const short8*)(qp);
        qf[mi][1] = *(const short8*)(qp + 32);
    }

    for (int e = tid; e < 64 * 64; e += 256) {
        int rr = e >> 6, cc = e & 63;
        float v = 0.f;
        if (rr < 27)      v = 8.f * relh[rr * 64 + cc];
        else if (rr < 54) v = 8.f * relw[(rr - 27) * 64 + cc];
        Kc[rr * AT_W + cc] = f2b(v);
    }
    if (tid < 128) {
        u16* rp = rel_ext + tid * 32;
        uint4 z = make_uint4(0u, 0u, 0u, 0u);
        *(uint4*)(rp) = z; *(uint4*)(rp + 8) = z;
        *(uint4*)(rp + 16) = z; *(uint4*)(rp + 24) = z;
        rp[31] = f2b(-1e30f);
    }
    __syncthreads();

#pragma unroll
    for (int cb = 0; cb < 2; cb++) {
#pragma unroll
        for (int nt = 0; nt < 2; nt++) {
            const u16* kp_ = Kc + (cb * 32 + nt * 16 + l16) * AT_W + quad * 8;
            short8 b0 = *(const short8*)(kp_);
            short8 b1 = *(const short8*)(kp_ + 32);
            int i = cb * 32 + nt * 16 + l16;
#pragma unroll
            for (int mi = 0; mi < 2; mi++) {
                f32x4 c = {};
                c = __builtin_amdgcn_mfma_f32_16x16x32_bf16(qf[mi][0], b0, c, 0, 0, 0);
                c = __builtin_amdgcn_mfma_f32_16x16x32_bf16(qf[mi][1], b1, c, 0, 0, 0);
#pragma unroll
                for (int r = 0; r < 4; r++) {
                    int row = wave * 32 + mi * 16 + quad * 4 + r;
                    int grow = row0 + row;
                    int rowB = grow < 196 ? grow : 195;
                    int p = rowB / 14, qq = rowB % 14;
                    if (i < 27) {
                        int t = p + 13 - i;
                        if (t >= 0 && t < 14) rel_ext[row * 32 + t] = f2b(c[r]);
                    } else if (i < 54) {
                        int t = qq + 13 - (i - 27);
                        if (t >= 0 && t < 14) rel_ext[row * 32 + 14 + t] = f2b(c[r]);
                    }
                }
            }
        }
    }
    short8 qe[2];
#pragma unroll
    for (int mi = 0; mi < 2; mi++)
        qe[mi] = *(const short8*)(rel_ext + (wave * 32 + mi * 16 + l16) * 32 + quad * 8);

    f32x4 acc[2][4] = {};
    float ml_[2][4], ll_[2][4];
#pragma unroll
    for (int mi = 0; mi < 2; mi++)
#pragma unroll
        for (int r = 0; r < 4; r++) { ml_[mi][r] = -1e30f; ll_[mi][r] = 0.f; }

#pragma unroll 1
    for (int c = 0; c < 4; c++) {
        const int kbase = c * 64;
        __syncthreads();
        {
            int key = tid >> 2;
            int cg  = (tid & 3) << 4;
            int gk = kbase + key;
            uint4 k0 = make_uint4(0u,0u,0u,0u), k1 = k0, v0 = k0, v1 = k0;
            if (gk < 196) {
                const u16* kp_ = qkv + base + 768  + (size_t)gk * 2304 + cg;
                const u16* vp_ = qkv + base + 1536 + (size_t)gk * 2304 + cg;
                k0 = *(const uint4*)(kp_); k1 = *(const uint4*)(kp_ + 8);
                v0 = *(const uint4*)(vp_); v1 = *(const uint4*)(vp_ + 8);
            }
            *(uint4*)(Kc + key * AT_W + cg)     = k0;
            *(uint4*)(Kc + key * AT_W + cg + 8) = k1;
            union { uint4 u; u16 h[8]; } a, b; a.u = v0; b.u = v1;
#pragma unroll
            for (int i = 0; i < 8; i++) Vt[(cg + i) * AT_W + key] = a.h[i];
#pragma unroll
            for (int i = 0; i < 8; i++) Vt[(cg + 8 + i) * AT_W + key] = b.h[i];
        }
        __syncthreads();

        short8 bo[4];
        {
            const u16 one = 0x3F80;
#pragma unroll
            for (int nt = 0; nt < 4; nt++) {
                int key = kbase + nt * 16 + l16;
                int inval = key >= 196;
                int kp = key / 14, kq = key - kp * 14;
                union { short8 s; u16 h[8]; } u;
#pragma unroll
                for (int j = 0; j < 8; j++) {
                    int t = quad * 8 + j;
                    u16 v = 0;
                    if (!inval && t == kp) v = one;
                    if (!inval && t >= 14 && (t - 14) == kq) v = one;
                    if (inval && t == 31) v = one;
                    u.h[j] = v;
                }
                bo[nt] = u.s;
            }
        }

        f32x4 s23[2][2];
#pragma unroll
        for (int mi = 0; mi < 2; mi++) {
            f32x4 s[4];
            __builtin_amdgcn_s_setprio(1);
#pragma unroll
            for (int nt = 0; nt < 4; nt++) {
                const u16* kp_ = Kc + (nt * 16 + l16) * AT_W + quad * 8;
                short8 kf0 = *(const short8*)(kp_);
                short8 kf1 = *(const short8*)(kp_ + 32);
                f32x4 t = {};
                t = __builtin_amdgcn_mfma_f32_16x16x32_bf16(qf[mi][0], kf0, t, 0, 0, 0);
                t = __builtin_amdgcn_mfma_f32_16x16x32_bf16(qf[mi][1], kf1, t, 0, 0, 0);
                t = __builtin_amdgcn_mfma_f32_16x16x32_bf16(qe[mi],    bo[nt], t, 0, 0, 0);
                s[nt] = t * 0.125f;
            }
            __builtin_amdgcn_s_setprio(0);
#pragma unroll
            for (int r = 0; r < 4; r++) {
                float mx = fmaxf(fmaxf(s[0][r], s[1][r]), fmaxf(s[2][r], s[3][r]));
#pragma unroll
                for (int off = 8; off; off >>= 1) mx = fmaxf(mx, __shfl_xor(mx, off, 16));
                float mo = ml_[mi][r];
                float mn = fmaxf(mo, mx);
                float alpha = __expf(mo - mn);
                ml_[mi][r] = mn;
                float p0 = __expf(s[0][r] - mn), p1 = __expf(s[1][r] - mn);
                float p2 = __expf(s[2][r] - mn), p3 = __expf(s[3][r] - mn);
                float ps = (p0 + p1) + (p2 + p3);
#pragma unroll
                for (int off = 8; off; off >>= 1) ps += __shfl_xor(ps, off, 16);
                ll_[mi][r] = ll_[mi][r] * alpha + ps;
#pragma unroll
                for (int ni = 0; ni < 4; ni++) acc[mi][ni][r] *= alpha;
                s[0][r] = p0; s[1][r] = p1; s[2][r] = p2; s[3][r] = p3;
            }
#pragma unroll
            for (int nt = 0; nt < 2; nt++)
#pragma unroll
                for (int r = 0; r < 4; r++)
                    pbuf[wave][(mi * 16 + quad * 4 + r) * PB_W + nt * 16 + l16] = f2b(s[nt][r]);
            s23[mi][0] = s[2]; s23[mi][1] = s[3];
        }

        __builtin_amdgcn_s_setprio(1);
#pragma unroll
        for (int mi = 0; mi < 2; mi++) {
            short8 pf = *(const short8*)(pbuf[wave] + (mi * 16 + l16) * PB_W + quad * 8);
#pragma unroll
            for (int ni = 0; ni < 4; ni++) {
                short8 vfn = *(const short8*)(Vt + (ni * 16 + l16) * AT_W + quad * 8);
                acc[mi][ni] = __builtin_amdgcn_mfma_f32_16x16x32_bf16(pf, vfn, acc[mi][ni], 0, 0, 0);
            }
        }
        __builtin_amdgcn_s_setprio(0);
#pragma unroll
        for (int mi = 0; mi < 2; mi++)
#pragma unroll
            for (int h = 0; h < 2; h++)
#pragma unroll
                for (int r = 0; r < 4; r++)
                    pbuf[wave][(mi * 16 + quad * 4 + r) * PB_W + h * 16 + l16] = f2b(s23[mi][h][r]);
        __builtin_amdgcn_s_setprio(1);
#pragma unroll
        for (int mi = 0; mi < 2; mi++) {
            short8 pf = *(const short8*)(pbuf[wave] + (mi * 16 + l16) * PB_W + quad * 8);
#pragma unroll
            for (int ni = 0; ni < 4; ni++) {
                short8 vfn = *(const short8*)(Vt + (ni * 16 + l16) * AT_W + 32 + quad * 8);
                acc[mi][ni] = __builtin_amdgcn_mfma_f32_16x16x32_bf16(pf, vfn, acc[mi][ni], 0, 0, 0);
            }
        }
        __builtin_amdgcn_s_setprio(0);
    }

#pragma unroll
    for (int mi = 0; mi < 2; mi++)
#pragma unroll
        for (int r = 0; r < 4; r++) {
            int tok = row0 + wave * 32 + mi * 16 + quad * 4 + r;
            if (tok < 196) {
                float inv = 1.f / ll_[mi][r];
                size_t ob = (size_t)(win * 196 + tok) * 768 + head * 64;
#pragma unroll
                for (int ni = 0; ni < 4; ni++)
                    out[ob + ni * 16 + l16] = f2b(acc[mi][ni][r] * inv);
            }
        }
}

// ---------------------------------------------------------------- launch
extern "C" void kernel_launch(void* const* d_in, const int* in_sizes, int n_in,
                              void* d_out, int out_size, void* d_ws, size_t ws_size,
                              hipStream_t stream)
{
    const float* x      = (const float*)d_in[0];
    const float* g1     = (const float*)d_in[1];
    const float* beta1  = (const float*)d_in[2];
    const float* w_qkv  = (const float*)d_in[3];
    const float* b_qkv  = (const float*)d_in[4];
    const float* w_proj = (const float*)d_in[5];
    const float* b_proj = (const float*)d_in[6];
    const float* rph    = (const float*)d_in[7];
    const float* rpw    = (const float*)d_in[8];
    const float* g2     = (const float*)d_in[9];
    const float* beta2  = (const float*)d_in[10];
    const float* w_fc1  = (const float*)d_in[11];
    const float* b_fc1  = (const float*)d_in[12];
    const float* w_fc2  = (const float*)d_in[13];
    const float* b_fc2  = (const float*)d_in[14];
    float* out = (float*)d_out;

    const size_t WT = 14155776;
    size_t b1 = 0, b2 = 0;
    int nc = 0, mc = 0;
    auto fits = [&](int a, int m) -> bool {
        size_t rows = (size_t)(200 / a) * 196, toks = (size_t)32768 / m;
        size_t bb1 = rows * 768 * 2 >= toks * 768 * 2 ? rows * 768 * 2 : toks * 768 * 2;
        size_t bb2 = rows * 2304 * 2 >= toks * 3072 * 2 ? rows * 2304 * 2 : toks * 3072 * 2;
        if (WT + bb1 + bb2 <= ws_size) { b1 = bb1; b2 = bb2; nc = a; mc = m; return true; }
        return false;
    };
    if (!fits(1, 1) && !fits(1, 2) && !fits(2, 2) && !fits(2, 4) && !fits(4, 4))
        return;   // diagnostic: leaves d_out untouched

    char* ws = (char*)d_ws;
    u16* wt0 = (u16*)ws;                               // qkv^T  2304x768
    u16* wt1 = wt0 + 2304 * 768;                       // proj^T  768x768
    u16* wt2 = wt1 + 768 * 768;                        // fc1^T  3072x768
    u16* wt3 = wt2 + 3072 * 768;                       // fc2^T   768x3072
    u16* buf1 = (u16*)(ws + WT);
    u16* buf2 = (u16*)(ws + WT + b1);

    dim3 blk(256);

    transpose_k<<<(768/32)*(2304/32), blk, 0, stream>>>(w_qkv,  wt0, 768, 2304);
    transpose_k<<<(768/32)*(768/32),  blk, 0, stream>>>(w_proj, wt1, 768, 768);
    transpose_k<<<(768/32)*(3072/32), blk, 0, stream>>>(w_fc1,  wt2, 768, 3072);
    transpose_k<<<(3072/32)*(768/32), blk, 0, stream>>>(w_fc2,  wt3, 3072, 768);

    // ---- attention phase: nc chunks of (200/nc) windows ----
    {
        const int nw = 200 / nc, rows = nw * 196;
        const int mt = (rows + 127) / 128;
        for (int c = 0; c < nc; c++) {
            const int rb = c * rows;
            ln_kernel<<<rows, blk, 0, stream>>>(x, g1, beta1, buf1, 1, rb);
            gemm_bt<0><<<dim3(mt * (2304/128)), blk, 0, stream>>>(
                buf1, wt0, b_qkv, buf2, nullptr, rows, 2304, 768, 0);
            attn_mfma<<<nw * 24, blk, 0, stream>>>(buf2, rph, rpw, buf1);
            gemm_bt<1><<<dim3(mt * (768/128)), blk, 0, stream>>>(
                buf1, wt1, b_proj, out, x, rows, 768, 768, rb);
        }
    }

    // ---- MLP phase: mc chunks of (32768/mc) tokens ----
    {
        const int tk = 32768 / mc;
        const int mt2 = tk / 128;
        for (int c = 0; c < mc; c++) {
            const int rb = c * tk;
            ln_kernel<<<tk, blk, 0, stream>>>(
                out + (size_t)rb * 768, g2, beta2, buf1, 0, 0);
            gemm_bt<2><<<dim3(mt2 * (3072/128)), blk, 0, stream>>>(
                buf1, wt2, b_fc1, buf2, nullptr, tk, 3072, 768, 0);
            gemm_bt<3><<<dim3(mt2 * (768/128)), blk, 0, stream>>>(
                buf2, wt3, b_fc2, out, out, tk, 768, 3072, rb);
        }
    }
}